// Round 2
// baseline (571.675 us; speedup 1.0000x reference)
//
#include <hip/hip_runtime.h>
#include <hip/hip_bf16.h>
#include <stdint.h>

// Sizes (fixed by the problem)
#define NN 512
#define DD 128
#define EE 16384

typedef short bf16x8 __attribute__((ext_vector_type(8)));
typedef short bf16x4 __attribute__((ext_vector_type(4)));
typedef float f32x4  __attribute__((ext_vector_type(4)));
typedef unsigned int u32;

__device__ __forceinline__ short f2bf(float f) {
    union { __hip_bfloat16 h; short s; } u;
    u.h = __float2bfloat16(f);
    return u.s;
}

// async global->LDS 16B copy. LDS dest = wave-uniform base + lane*16 (linear in
// tid); XOR swizzle is applied on the SOURCE chunk index.
typedef __attribute__((address_space(3))) unsigned int lds_u32;
typedef __attribute__((address_space(1))) const unsigned int glb_u32;
__device__ __forceinline__ void gll16(void* l, const void* g) {
    __builtin_amdgcn_global_load_lds((glb_u32*)g, (lds_u32*)l, 16, 0, 0);
}

// ---------------- tiny prep kernels ----------------

__global__ void k_zero(float* __restrict__ At) {
    At[blockIdx.x * 256 + threadIdx.x] = 0.0f;
}

// Build At[dst][src] += 1.  Robust to int32 or int64 input (for int64 LE every
// odd 32-bit word is 0 since values < 512).
__global__ void k_edges(const int* __restrict__ ei, float* __restrict__ At) {
    __shared__ int flag;
    if (threadIdx.x == 0) flag = 0;
    __syncthreads();
    int any = 0;
    for (int i = threadIdx.x; i < EE; i += blockDim.x) any |= ei[2 * i + 1];
    if (any) atomicOr(&flag, 1);
    __syncthreads();
    const bool is32 = (flag != 0);
    for (int e = threadIdx.x; e < EE; e += blockDim.x) {
        int src, dst;
        if (is32) { src = ei[e];     dst = ei[EE + e]; }
        else      { src = ei[2 * e]; dst = ei[2 * (EE + e)]; }
        atomicAdd(&At[dst * NN + src], 1.0f);
    }
}

// Wt2[s][n][d] = bf16(W[(s*128+d)*128 + n])   (used by k_a2f for W0 staging)
__global__ void k_wt2(const float* __restrict__ W, short* __restrict__ Wt2) {
    int t = blockIdx.x * 256 + threadIdx.x;     // t = kk*128 + n, kk = s*128+d
    int kk = t >> 7, n = t & 127;
    int s = kk >> 7, d = kk & 127;
    Wt2[s * 16384 + n * 128 + d] = f2bf(W[t]);
}

// Pack At into MFMA A-fragment tile order: tile T = jt*16 + kt covers rows
// jt*16..+16, cols kt*32..+32; lane l holds At[jt*16 + (l&15)][kt*32 + (l>>4)*8 + e].
// A wave's fragment load is then 64 lanes x 16B contiguous (1 KB), L2-resident.
__global__ void k_pack_at(const float* __restrict__ At, short* __restrict__ Atp) {
    int t = blockIdx.x * 256 + threadIdx.x;     // 32768 threads
    int T = t >> 6, l = t & 63;
    int row = (T >> 4) * 16 + (l & 15);
    int col = (T & 15) * 32 + (l >> 4) * 8;
    const float* s = &At[row * 512 + col];
    bf16x8 p;
    #pragma unroll
    for (int e = 0; e < 8; ++e) p[e] = f2bf(s[e]);
    *(bf16x8*)&Atp[(size_t)T * 512 + l * 8] = p;
}

// Pack W1,W2 into MFMA B-fragment tile order (B^T convention used throughout:
// lane holds W[n = nt*16 + (l&15)][d = kt*32 + (l>>4)*8 + e]).
// T = (s*8 + nt)*4 + kt, s=0 -> W1, s=1 -> W2.  64 tiles x 1 KB = 64 KB, L2-hot.
__global__ void k_pack_w(const float* __restrict__ W, short* __restrict__ Wp) {
    int t = blockIdx.x * 256 + threadIdx.x;     // 4096 threads
    int T = t >> 6, l = t & 63;
    int s = T >> 5, nt = (T >> 2) & 7, kt = T & 3;
    int n  = nt * 16 + (l & 15);
    int d0 = kt * 32 + (l >> 4) * 8;
    bf16x8 p;
    #pragma unroll
    for (int e = 0; e < 8; ++e)
        p[e] = f2bf(W[((1 + s) * 128 + d0 + e) * 128 + n]);
    *(bf16x8*)&Wp[(size_t)T * 512 + l * 8] = p;
}

// ---------------- k_slab: fused Y1/Y2/partial, one block per i ----------------
// Per i: Xc chunk (128 rows) staged bf16 -> LDS; Y1c = Xc@W1 kept in LDS only;
// Y2c = Xc@W2 -> global via LDS roundtrip (coalesced 16B stores);
// partial[i] = At @ Y1[i] accumulated across chunks in registers.
// W and At fragments read direct from packed global buffers (L2-hot), so LDS is
// only 64 KB -> 2 blocks/CU for barrier overlap.
__global__ __launch_bounds__(512, 2) void k_slab(const float* __restrict__ X,
                                                 const short* __restrict__ Wp,
                                                 const short* __restrict__ Atp,
                                                 short* __restrict__ Y2,
                                                 short* __restrict__ Pp) {
    __shared__ __align__(16) short sh[32768];   // 64 KB
    short* Xc = sh;              // [0,16384):   [kb][r 0..127][64 sw]; Y2 scratch
    short* Yc = sh + 16384;      // [16384,32768): Y1c n-major [kb2][n][64 sw]

    const int tid  = threadIdx.x;
    const int lane = tid & 63;
    const int wv   = tid >> 6;
    const int lm   = lane & 15;
    const int lq   = lane >> 4;
    const int i    = blockIdx.x;

    // phase A roles: wave -> (matrix, quadrant) of the 128x128 chunk product
    const int mw   = wv & 1;          // 0 -> W1 (to Yc), 1 -> W2 (to global)
    const int quad = wv >> 1;
    const int rowh = quad & 1;        // row half (x64)
    const int colh = quad >> 1;       // col half (x64)
    // phase B: wave owns partial rows wr..wr+64
    const int wr   = wv * 64;

    f32x4 acc[4][8] = {};

    for (int kc = 0; kc < 4; ++kc) {
        if (kc) __syncthreads();     // prior phase-B Yc reads / copy-out reads done
        // stage Xc: rows kc*128..+128, fp32 -> bf16, swizzled
        #pragma unroll
        for (int it = 0; it < 8; ++it) {
            int g = tid + it * 512;
            int r = g >> 5, c4 = g & 31;
            float4 v = *(const float4*)&X[(size_t)i * 65536 + (kc * 128 + r) * 128 + c4 * 4];
            int kb = c4 >> 4, c = c4 & 15, p = c >> 1, h2 = c & 1;
            bf16x4 pcv; pcv[0] = f2bf(v.x); pcv[1] = f2bf(v.y); pcv[2] = f2bf(v.z); pcv[3] = f2bf(v.w);
            *(bf16x4*)&Xc[kb * 8192 + r * 64 + ((p ^ (r & 7)) * 8 + h2 * 4)] = pcv;
        }
        __syncthreads();             // Xc visible

        // ---- phase A: quadrant (rowh,colh) of Xc @ W[mw], B-frags from L2 ----
        f32x4 ay[4][4] = {};
        #pragma unroll
        for (int sl = 0; sl < 4; ++sl) {
            int kb = sl >> 1, ks = sl & 1, Cc = ks * 4 + lq;
            int kt = kb * 2 + ks;
            bf16x8 af[4], bw[4];
            #pragma unroll
            for (int mf = 0; mf < 4; ++mf) {
                int R = rowh * 64 + mf * 16 + lm;
                af[mf] = *(const bf16x8*)&Xc[kb * 8192 + R * 64 + ((Cc ^ (R & 7)) * 8)];
            }
            #pragma unroll
            for (int nf = 0; nf < 4; ++nf)
                bw[nf] = *(const bf16x8*)&Wp[(size_t)(((mw * 8) + colh * 4 + nf) * 4 + kt) * 512 + lane * 8];
            #pragma unroll
            for (int mf = 0; mf < 4; ++mf)
                #pragma unroll
                for (int nf = 0; nf < 4; ++nf)
                    ay[mf][nf] = __builtin_amdgcn_mfma_f32_16x16x32_bf16(
                        af[mf], bw[nf], ay[mf][nf], 0, 0, 0);
        }
        __syncthreads();             // all Xc reads done -> Xc reusable as scratch

        if (mw == 0) {
            // Y1c quadrant -> Yc, n-major with the standard group swizzle
            #pragma unroll
            for (int mf = 0; mf < 4; ++mf)
                #pragma unroll
                for (int nf = 0; nf < 4; ++nf)
                    #pragma unroll
                    for (int rr = 0; rr < 4; ++rr) {
                        int rl64 = mf * 16 + lq * 4 + rr;          // k within 64-half
                        int n = colh * 64 + nf * 16 + lm;
                        Yc[rowh * 8192 + n * 64 + (((rl64 >> 3) ^ (n & 7)) * 8 + (rl64 & 7))]
                            = f2bf(ay[mf][nf][rr]);
                    }
        } else {
            // Y2c quadrant -> Xc scratch, natural [r][n]
            #pragma unroll
            for (int mf = 0; mf < 4; ++mf)
                #pragma unroll
                for (int nf = 0; nf < 4; ++nf)
                    #pragma unroll
                    for (int rr = 0; rr < 4; ++rr) {
                        int r = rowh * 64 + mf * 16 + lq * 4 + rr;
                        int n = colh * 64 + nf * 16 + lm;
                        Xc[r * 128 + n] = f2bf(ay[mf][nf][rr]);
                    }
        }
        __syncthreads();             // Yc + Y2 scratch complete

        // copy-out Y2 chunk: coalesced 16B stores (fire-and-forget)
        #pragma unroll
        for (int it = 0; it < 4; ++it) {
            int q = tid + it * 512;
            int row = q >> 4, oc = (q & 15) * 8;
            *(bf16x8*)&Y2[(size_t)i * 65536 + (kc * 128 + row) * 128 + oc]
                = *(const bf16x8*)&Xc[row * 128 + oc];
        }

        // ---- phase B: acc += At[wr..wr+64, kc*128..+128] @ Y1c ----
        #pragma unroll
        for (int kb2 = 0; kb2 < 2; ++kb2)
            #pragma unroll
            for (int ks = 0; ks < 2; ++ks) {
                int kt = kc * 4 + kb2 * 2 + ks;
                bf16x8 af[4], bf[8];
                #pragma unroll
                for (int mf = 0; mf < 4; ++mf)
                    af[mf] = *(const bf16x8*)&Atp[(size_t)((wv * 4 + mf) * 16 + kt) * 512 + lane * 8];
                #pragma unroll
                for (int nf = 0; nf < 8; ++nf) {
                    int R = nf * 16 + lm;
                    bf[nf] = *(const bf16x8*)&Yc[kb2 * 8192 + R * 64 + (((ks * 4 + lq) ^ (R & 7)) * 8)];
                }
                #pragma unroll
                for (int mf = 0; mf < 4; ++mf)
                    #pragma unroll
                    for (int nf = 0; nf < 8; ++nf)
                        acc[mf][nf] = __builtin_amdgcn_mfma_f32_16x16x32_bf16(
                            af[mf], bf[nf], acc[mf][nf], 0, 0, 0);
            }
    }

    // epilogue: partial[i] bf16, coalesced via LDS roundtrip in two half-passes
    #pragma unroll
    for (int half = 0; half < 2; ++half) {
        __syncthreads();
        if ((wv >> 2) == half) {
            int lrb = (wv & 3) * 64;
            #pragma unroll
            for (int mf = 0; mf < 4; ++mf)
                #pragma unroll
                for (int nf = 0; nf < 8; ++nf)
                    #pragma unroll
                    for (int rr = 0; rr < 4; ++rr)
                        sh[(lrb + mf * 16 + lq * 4 + rr) * 128 + nf * 16 + lm]
                            = f2bf(acc[mf][nf][rr]);
        }
        __syncthreads();
        #pragma unroll
        for (int it = 0; it < 8; ++it) {
            int q = tid + it * 512;
            int row = q >> 4, oc = (q & 15) * 8;
            *(bf16x8*)&Pp[(size_t)i * 65536 + (half * 256 + row) * 128 + oc]
                = *(const bf16x8*)&sh[row * 128 + oc];
        }
    }
}

// ---------------- k_t: bf16 transpose Y2[k][j][n] -> Y2T[j][n][k] ----------------
__global__ __launch_bounds__(256) void k_t(const short* __restrict__ Y2,
                                           short* __restrict__ Y2T) {
    __shared__ __align__(16) u32 U[128 * 64];   // U[n][a]: (k=2a, 2a+1) packed
    const int tid = threadIdx.x;
    const int j  = blockIdx.x >> 2;
    const int k0 = (blockIdx.x & 3) * 128;

    const int c8 = tid & 15;         // 8-n chunk
    const int a0 = tid >> 4;         // pair index base
    #pragma unroll
    for (int it = 0; it < 4; ++it) {
        int a = a0 + it * 16;        // 0..63
        const short* r0 = &Y2[(size_t)(k0 + 2 * a) * 65536 + j * 128 + c8 * 8];
        bf16x8 A0 = *(const bf16x8*)r0;
        bf16x8 A1 = *(const bf16x8*)(r0 + 65536);
        #pragma unroll
        for (int cc = 0; cc < 8; ++cc) {
            int n = c8 * 8 + cc;
            U[n * 64 + (a ^ (n & 28))] =
                (u32)(unsigned short)A0[cc] | ((u32)(unsigned short)A1[cc] << 16);
        }
    }
    __syncthreads();
    const int ch = tid & 15;
    const int n0 = tid >> 4;
    #pragma unroll
    for (int it = 0; it < 8; ++it) {
        int n = n0 + it * 16;
        uint4 q = *(const uint4*)&U[n * 64 + ((ch * 4) ^ (n & 28))];
        *(uint4*)&Y2T[j * 65536 + n * 512 + k0 + ch * 8] = q;
    }
}

// ---------------- k_a2f: out = At@Y2T + X@W0 + partial + b ----------------
// block b: j = b>>2, i0 = (b&3)*128. At fragments read direct from packed Atp.
__global__ __launch_bounds__(256) void k_a2f(const float* __restrict__ X,
                                             const short* __restrict__ Atp,
                                             const short* __restrict__ Y2T,
                                             const short* __restrict__ Wt2,
                                             const short* __restrict__ Pp,
                                             const float* __restrict__ bias,
                                             float* __restrict__ out) {
    __shared__ __align__(16) short sm[16384];
    short* As = sm;
    short* Bs = sm + 8192;

    const int tid  = threadIdx.x;
    const int lane = tid & 63;
    const int wv   = tid >> 6;
    const int wr   = (wv >> 1) * 64;
    const int wc   = (wv & 1) * 64;
    const int lm   = lane & 15;
    const int lq   = lane >> 4;
    const int j  = blockIdx.x >> 2;
    const int i0 = (blockIdx.x & 3) * 128;

    f32x4 acc[4][4] = {};

    // ---- phase 1: X@W0, K=128 ----
    #pragma unroll
    for (int kb = 0; kb < 2; ++kb) {
        #pragma unroll
        for (int it = 0; it < 8; ++it) {
            int g = tid + it * 256;
            int r = g >> 4, c4 = g & 15;
            float4 v = *(const float4*)&X[(size_t)(i0 + r) * 65536 + j * 128 + kb * 64 + c4 * 4];
            int p = c4 >> 1, h2 = c4 & 1;
            bf16x4 pc; pc[0] = f2bf(v.x); pc[1] = f2bf(v.y); pc[2] = f2bf(v.z); pc[3] = f2bf(v.w);
            *(bf16x4*)&As[r * 64 + ((p ^ (r & 7)) * 8 + h2 * 4)] = pc;
        }
        #pragma unroll
        for (int it = 0; it < 4; ++it) {
            int slot = it * 256 + tid;
            int n = slot >> 3, pc = slot & 7;
            gll16(&Bs[slot * 8], &Wt2[n * 128 + kb * 64 + ((pc ^ (n & 7)) * 8)]);
        }
        __syncthreads();
        #pragma unroll
        for (int ks = 0; ks < 2; ++ks) {
            bf16x8 af[4], bf[4];
            #pragma unroll
            for (int mf = 0; mf < 4; ++mf) {
                int R = wr + mf * 16 + lm, Cc = ks * 4 + lq;
                af[mf] = *(const bf16x8*)&As[R * 64 + (Cc ^ (R & 7)) * 8];
            }
            #pragma unroll
            for (int nf = 0; nf < 4; ++nf) {
                int R = wc + nf * 16 + lm, Cc = ks * 4 + lq;
                bf[nf] = *(const bf16x8*)&Bs[R * 64 + (Cc ^ (R & 7)) * 8];
            }
            #pragma unroll
            for (int mf = 0; mf < 4; ++mf)
                #pragma unroll
                for (int nf = 0; nf < 4; ++nf)
                    acc[mf][nf] = __builtin_amdgcn_mfma_f32_16x16x32_bf16(
                        af[mf], bf[nf], acc[mf][nf], 0, 0, 0);
        }
        __syncthreads();
    }

    // ---- phase 2: At@Y2T, K=512; A-fragments direct from packed global ----
    const int jt0 = (i0 >> 4) + (wr >> 4);
    for (int kb = 0; kb < 8; ++kb) {
        const int k0 = kb * 64;
        #pragma unroll
        for (int it = 0; it < 4; ++it) {
            int slot = it * 256 + tid;
            int r = slot >> 3, p = slot & 7;
            int cg = (p ^ (r & 7)) * 8;
            gll16(&Bs[slot * 8], &Y2T[j * 65536 + r * 512 + k0 + cg]);
        }
        __syncthreads();
        #pragma unroll
        for (int ks = 0; ks < 2; ++ks) {
            int kt = kb * 2 + ks;
            bf16x8 af[4], bf[4];
            #pragma unroll
            for (int mf = 0; mf < 4; ++mf)
                af[mf] = *(const bf16x8*)&Atp[(size_t)((jt0 + mf) * 16 + kt) * 512 + lane * 8];
            #pragma unroll
            for (int nf = 0; nf < 4; ++nf) {
                int R = wc + nf * 16 + lm, Cc = ks * 4 + lq;
                bf[nf] = *(const bf16x8*)&Bs[R * 64 + (Cc ^ (R & 7)) * 8];
            }
            #pragma unroll
            for (int mf = 0; mf < 4; ++mf)
                #pragma unroll
                for (int nf = 0; nf < 4; ++nf)
                    acc[mf][nf] = __builtin_amdgcn_mfma_f32_16x16x32_bf16(
                        af[mf], bf[nf], acc[mf][nf], 0, 0, 0);
        }
        __syncthreads();
    }

    // ---- fused epilogue: + partial + bias -> fp32 out ----
    #pragma unroll
    for (int mf = 0; mf < 4; ++mf)
        #pragma unroll
        for (int nf = 0; nf < 4; ++nf)
            #pragma unroll
            for (int r = 0; r < 4; ++r)
                sm[(wr + mf * 16 + lq * 4 + r) * 128 + wc + nf * 16 + lm]
                    = f2bf(acc[mf][nf][r]);
    __syncthreads();
    #pragma unroll
    for (int it = 0; it < 8; ++it) {
        int q = tid + it * 256;
        int row = q >> 4, oc = (q & 15) * 8;
        bf16x8 vs = *(const bf16x8*)&sm[row * 128 + oc];
        bf16x8 vpl = *(const bf16x8*)&Pp[(size_t)(i0 + row) * 65536 + j * 128 + oc];
        float4 b0 = *(const float4*)&bias[oc];
        float4 b1 = *(const float4*)&bias[oc + 4];
        union { short s; __hip_bfloat16 h; } cs, cp;
        float o[8];
        #pragma unroll
        for (int e = 0; e < 8; ++e) {
            cs.s = vs[e]; cp.s = vpl[e];
            o[e] = __bfloat162float(cs.h) + __bfloat162float(cp.h);
        }
        o[0] += b0.x; o[1] += b0.y; o[2] += b0.z; o[3] += b0.w;
        o[4] += b1.x; o[5] += b1.y; o[6] += b1.z; o[7] += b1.w;
        float* op = &out[(size_t)(i0 + row) * 65536 + j * 128 + oc];
        float4 w0; w0.x = o[0]; w0.y = o[1]; w0.z = o[2]; w0.w = o[3];
        float4 w1; w1.x = o[4]; w1.y = o[5]; w1.z = o[6]; w1.w = o[7];
        *(float4*)op = w0;
        *(float4*)(op + 4) = w1;
    }
}

// ================= fallback path (round-1, proven, 130 MiB ws) =================

__global__ __launch_bounds__(256) void k_agg_fb(const float* __restrict__ X,
                                                const float* __restrict__ At,
                                                short* __restrict__ X1b,
                                                short* __restrict__ X2b) {
    __shared__ short As[128 * 72];
    __shared__ short Bs[128 * 72];
    const int tid  = threadIdx.x;
    const int lane = tid & 63;
    const int wv   = tid >> 6;
    const int wr   = (wv >> 1) * 64;
    const int wc   = (wv & 1) * 64;
    const int lm   = lane & 15;
    const int lq   = lane >> 4;
    int a0, Bbase, Bks, Cbase, Crs;
    short* Cp;
    const int bidx = blockIdx.x;
    if (bidx < 2048) {
        int i = bidx >> 2, jt = bidx & 3;
        a0 = jt * 128; Bbase = i * 65536; Bks = 128;
        Cbase = i * 65536 + jt * 16384; Crs = 128; Cp = X1b;
    } else {
        int bb = bidx - 2048;
        int j = bb >> 2, it = bb & 3;
        a0 = it * 128; Bbase = j * 128; Bks = 65536;
        Cbase = it * 8388608 + j * 128; Crs = 65536; Cp = X2b;
    }
    f32x4 acc[4][4] = {};
    const int d  = tid & 127;
    const int kh = tid >> 7;
    for (int kb = 0; kb < 8; ++kb) {
        const int k0 = kb * 64;
        #pragma unroll
        for (int it8 = 0; it8 < 8; ++it8) {
            int g = tid + it8 * 256;
            int r = g >> 4, kq = (g & 15) * 4;
            float4 v = *(const float4*)&At[(a0 + r) * 512 + k0 + kq];
            bf16x4 p; p[0] = f2bf(v.x); p[1] = f2bf(v.y); p[2] = f2bf(v.z); p[3] = f2bf(v.w);
            *(bf16x4*)&As[r * 72 + kq] = p;
        }
        #pragma unroll
        for (int gi = 0; gi < 4; ++gi) {
            int kg = kh * 4 + gi;
            bf16x8 p;
            #pragma unroll
            for (int jj = 0; jj < 8; ++jj)
                p[jj] = f2bf(X[Bbase + (k0 + kg * 8 + jj) * Bks + d]);
            *(bf16x8*)&Bs[d * 72 + kg * 8] = p;
        }
        __syncthreads();
        #pragma unroll
        for (int ks = 0; ks < 2; ++ks) {
            bf16x8 af[4], bfr[4];
            #pragma unroll
            for (int mf = 0; mf < 4; ++mf)
                af[mf] = *(const bf16x8*)&As[(wr + mf * 16 + lm) * 72 + ks * 32 + lq * 8];
            #pragma unroll
            for (int nf = 0; nf < 4; ++nf)
                bfr[nf] = *(const bf16x8*)&Bs[(wc + nf * 16 + lm) * 72 + ks * 32 + lq * 8];
            #pragma unroll
            for (int mf = 0; mf < 4; ++mf)
                #pragma unroll
                for (int nf = 0; nf < 4; ++nf)
                    acc[mf][nf] = __builtin_amdgcn_mfma_f32_16x16x32_bf16(
                        af[mf], bfr[nf], acc[mf][nf], 0, 0, 0);
        }
        __syncthreads();
    }
    #pragma unroll
    for (int mf = 0; mf < 4; ++mf)
        #pragma unroll
        for (int nf = 0; nf < 4; ++nf)
            #pragma unroll
            for (int r = 0; r < 4; ++r) {
                int row = wr + mf * 16 + lq * 4 + r;
                int col = wc + nf * 16 + lm;
                Cp[Cbase + row * Crs + col] = f2bf(acc[mf][nf][r]);
            }
}

__global__ __launch_bounds__(256) void k_final_fb(const float* __restrict__ X,
                                                  const short* __restrict__ X1b,
                                                  const short* __restrict__ X2b,
                                                  const short* __restrict__ Wt2,
                                                  const float* __restrict__ bias,
                                                  float* __restrict__ out) {
    __shared__ short As[128 * 72];
    __shared__ short Ws[128 * 72];
    const int tid  = threadIdx.x;
    const int lane = tid & 63;
    const int wv   = tid >> 6;
    const int wr   = (wv >> 1) * 64;
    const int wc   = (wv & 1) * 64;
    const int lm   = lane & 15;
    const int lq   = lane >> 4;
    const int m0   = blockIdx.x * 128;
    f32x4 acc[4][4] = {};
    for (int ph = 0; ph < 6; ++ph) {
        const int s = ph >> 1, h = ph & 1;
        if (s == 0) {
            #pragma unroll
            for (int it8 = 0; it8 < 8; ++it8) {
                int g = tid + it8 * 256;
                int r = g >> 4, kq = (g & 15) * 4;
                float4 v = *(const float4*)&X[(m0 + r) * 128 + h * 64 + kq];
                bf16x4 p; p[0] = f2bf(v.x); p[1] = f2bf(v.y); p[2] = f2bf(v.z); p[3] = f2bf(v.w);
                *(bf16x4*)&As[r * 72 + kq] = p;
            }
        } else {
            const short* src = (s == 1) ? X1b : X2b;
            #pragma unroll
            for (int it4 = 0; it4 < 4; ++it4) {
                int g = tid + it4 * 256;
                int r = g >> 3, ko = (g & 7) * 8;
                *(bf16x8*)&As[r * 72 + ko] =
                    *(const bf16x8*)&src[(m0 + r) * 128 + h * 64 + ko];
            }
        }
        #pragma unroll
        for (int it4 = 0; it4 < 4; ++it4) {
            int g = tid + it4 * 256;
            int n = g >> 3, ko = (g & 7) * 8;
            *(bf16x8*)&Ws[n * 72 + ko] =
                *(const bf16x8*)&Wt2[s * 16384 + n * 128 + h * 64 + ko];
        }
        __syncthreads();
        #pragma unroll
        for (int ks = 0; ks < 2; ++ks) {
            bf16x8 af[4], bfr[4];
            #pragma unroll
            for (int mf = 0; mf < 4; ++mf)
                af[mf] = *(const bf16x8*)&As[(wr + mf * 16 + lm) * 72 + ks * 32 + lq * 8];
            #pragma unroll
            for (int nf = 0; nf < 4; ++nf)
                bfr[nf] = *(const bf16x8*)&Ws[(wc + nf * 16 + lm) * 72 + ks * 32 + lq * 8];
            #pragma unroll
            for (int mf = 0; mf < 4; ++mf)
                #pragma unroll
                for (int nf = 0; nf < 4; ++nf)
                    acc[mf][nf] = __builtin_amdgcn_mfma_f32_16x16x32_bf16(
                        af[mf], bfr[nf], acc[mf][nf], 0, 0, 0);
        }
        __syncthreads();
    }
    #pragma unroll
    for (int nf = 0; nf < 4; ++nf) {
        float bv = bias[wc + nf * 16 + lm];
        #pragma unroll
        for (int mf = 0; mf < 4; ++mf)
            #pragma unroll
            for (int r = 0; r < 4; ++r) {
                int row = m0 + wr + mf * 16 + lq * 4 + r;
                int col = wc + nf * 16 + lm;
                out[row * 128 + col] = acc[mf][nf][r] + bv;
            }
    }
}

extern "C" void kernel_launch(void* const* d_in, const int* in_sizes, int n_in,
                              void* d_out, int out_size, void* d_ws, size_t ws_size,
                              hipStream_t stream) {
    const float* X  = (const float*)d_in[0];
    const int*   ei = (const int*)d_in[1];
    const float* W  = (const float*)d_in[2];
    const float* b  = (const float*)d_in[3];
    float* out = (float*)d_out;
    char* ws = (char*)d_ws;
    const size_t MB = 1u << 20;

    float* At  = (float*)ws;                            // [0, 1M)
    short* Atp = (short*)(ws + 1 * MB);                 // [1M, 1.5M) packed A-frag
    short* Wt2 = (short*)(ws + 1 * MB + 512 * 1024);    // 96 KiB
    short* Wp  = (short*)(ws + 1 * MB + 640 * 1024);    // 64 KiB packed B-frag W1/W2

    k_zero   <<<1024, 256, 0, stream>>>(At);
    k_edges  <<<1, 1024, 0, stream>>>(ei, At);
    k_wt2    <<<192, 256, 0, stream>>>(W, Wt2);
    k_pack_at<<<128, 256, 0, stream>>>(At, Atp);
    k_pack_w <<<16, 256, 0, stream>>>(W, Wp);

    if (ws_size >= 194 * MB) {
        short* Y2  = (short*)(ws + 2 * MB);     // 64M: X@W2, natural [k][j][n]
        short* Y2T = (short*)(ws + 66 * MB);    // 64M: transposed [j][n][k]
        short* Pp  = (short*)(ws + 130 * MB);   // 64M: partial = At@(X@W1)
        k_slab<<<512, 512, 0, stream>>>(X, Wp, Atp, Y2, Pp);
        k_t   <<<2048, 256, 0, stream>>>(Y2, Y2T);
        k_a2f <<<2048, 256, 0, stream>>>(X, Atp, Y2T, Wt2, Pp, b, out);
    } else {
        short* X1b = (short*)(ws + 2 * MB);
        short* X2b = (short*)(ws + 66 * MB);
        k_agg_fb  <<<4096, 256, 0, stream>>>(X, At, X1b, X2b);
        k_final_fb<<<2048, 256, 0, stream>>>(X, X1b, X2b, Wt2, b, out);
    }
}

// Round 3
// 538.727 us; speedup vs baseline: 1.0612x; 1.0612x over previous
//
#include <hip/hip_runtime.h>
#include <hip/hip_bf16.h>
#include <stdint.h>

// Sizes (fixed by the problem)
#define NN 512
#define DD 128
#define EE 16384

typedef short bf16x8 __attribute__((ext_vector_type(8)));
typedef short bf16x4 __attribute__((ext_vector_type(4)));
typedef float f32x4  __attribute__((ext_vector_type(4)));
typedef unsigned int u32;

__device__ __forceinline__ short f2bf(float f) {
    union { __hip_bfloat16 h; short s; } u;
    u.h = __float2bfloat16(f);
    return u.s;
}

// async global->LDS 16B copy. LDS dest = wave-uniform base + lane*16 (linear in
// tid); XOR swizzle (when used) is applied on the SOURCE chunk index.
typedef __attribute__((address_space(3))) unsigned int lds_u32;
typedef __attribute__((address_space(1))) const unsigned int glb_u32;
__device__ __forceinline__ void gll16(void* l, const void* g) {
    __builtin_amdgcn_global_load_lds((glb_u32*)g, (lds_u32*)l, 16, 0, 0);
}

// ---------------- tiny prep kernels ----------------

__global__ void k_zero(float* __restrict__ At) {
    At[blockIdx.x * 256 + threadIdx.x] = 0.0f;
}

// Build At[dst][src] += 1.  Robust to int32 or int64 input (for int64 LE every
// odd 32-bit word is 0 since values < 512).
__global__ void k_edges(const int* __restrict__ ei, float* __restrict__ At) {
    __shared__ int flag;
    if (threadIdx.x == 0) flag = 0;
    __syncthreads();
    int any = 0;
    for (int i = threadIdx.x; i < EE; i += blockDim.x) any |= ei[2 * i + 1];
    if (any) atomicOr(&flag, 1);
    __syncthreads();
    const bool is32 = (flag != 0);
    for (int e = threadIdx.x; e < EE; e += blockDim.x) {
        int src, dst;
        if (is32) { src = ei[e];     dst = ei[EE + e]; }
        else      { src = ei[2 * e]; dst = ei[2 * (EE + e)]; }
        atomicAdd(&At[dst * NN + src], 1.0f);
    }
}

// Wt2[s][n][d] = bf16(W[(s*128+d)*128 + n])   (used by k_a2f for W0 staging)
__global__ void k_wt2(const float* __restrict__ W, short* __restrict__ Wt2) {
    int t = blockIdx.x * 256 + threadIdx.x;     // t = kk*128 + n, kk = s*128+d
    int kk = t >> 7, n = t & 127;
    int s = kk >> 7, d = kk & 127;
    Wt2[s * 16384 + n * 128 + d] = f2bf(W[t]);
}

// Pack At into MFMA A-fragment tile order: tile T = jt*16 + kt covers rows
// jt*16..+16, cols kt*32..+32; lane l holds At[jt*16 + (l&15)][kt*32 + (l>>4)*8 + e].
// A wave's fragment load is then 64 lanes x 16B contiguous (1 KB), L2-resident.
__global__ void k_pack_at(const float* __restrict__ At, short* __restrict__ Atp) {
    int t = blockIdx.x * 256 + threadIdx.x;     // 32768 threads
    int T = t >> 6, l = t & 63;
    int row = (T >> 4) * 16 + (l & 15);
    int col = (T & 15) * 32 + (l >> 4) * 8;
    const float* s = &At[row * 512 + col];
    bf16x8 p;
    #pragma unroll
    for (int e = 0; e < 8; ++e) p[e] = f2bf(s[e]);
    *(bf16x8*)&Atp[(size_t)T * 512 + l * 8] = p;
}

// Pack W1,W2 into MFMA B-fragment tile order (B^T convention used throughout:
// lane holds W[n = nt*16 + (l&15)][d = kt*32 + (l>>4)*8 + e]).
// T = (s*8 + nt)*4 + kt, s=0 -> W1, s=1 -> W2.  64 tiles x 1 KB = 64 KB.
__global__ void k_pack_w(const float* __restrict__ W, short* __restrict__ Wp) {
    int t = blockIdx.x * 256 + threadIdx.x;     // 4096 threads
    int T = t >> 6, l = t & 63;
    int s = T >> 5, nt = (T >> 2) & 7, kt = T & 3;
    int n  = nt * 16 + (l & 15);
    int d0 = kt * 32 + (l >> 4) * 8;
    bf16x8 p;
    #pragma unroll
    for (int e = 0; e < 8; ++e)
        p[e] = f2bf(W[((1 + s) * 128 + d0 + e) * 128 + n]);
    *(bf16x8*)&Wp[(size_t)T * 512 + l * 8] = p;
}

// ---------------- k_slab: fused Y1/Y2/partial, one block per i ----------------
// Per i: Xc chunk (128 rows) staged bf16 -> LDS; Y1c = Xc@W1 kept in LDS only;
// Y2c = Xc@W2 -> global via LDS roundtrip (coalesced 16B stores);
// partial[i] = At @ Y1[i] accumulated across chunks in registers.
// W fragment tiles staged ONCE into LDS (linear copy, conflict-free lane*16
// reads); At fragments direct from packed global (L2-hot).
// launch_bounds(512,1): VGPR cap 256 -> no scratch spill (acc[4][8]=128 regs).
__global__ __launch_bounds__(512, 1) void k_slab(const float* __restrict__ X,
                                                 const short* __restrict__ Wp,
                                                 const short* __restrict__ Atp,
                                                 short* __restrict__ Y2,
                                                 short* __restrict__ Pp) {
    __shared__ __align__(16) short sh[65536];   // 128 KB
    short* Xc = sh;              // [0,16384):  32 KB [kb][r 0..127][64 sw]; Y2 scratch
    short* Yc = sh + 16384;      // [16384,32768): 32 KB Y1c n-major [kb2][n][64 sw]
    short* Lw = sh + 32768;      // [32768,65536): 64 KB W1,W2 fragment tiles (linear)

    const int tid  = threadIdx.x;
    const int lane = tid & 63;
    const int wv   = tid >> 6;
    const int lm   = lane & 15;
    const int lq   = lane >> 4;
    const int i    = blockIdx.x;

    // phase A roles: wave -> (matrix, quadrant) of the 128x128 chunk product
    const int mw   = wv & 1;          // 0 -> W1 (to Yc), 1 -> W2 (to global)
    const int quad = wv >> 1;
    const int rowh = quad & 1;        // row half (x64)
    const int colh = quad >> 1;       // col half (x64)
    // phase B: wave owns partial rows wr..wr+64
    const int wr   = wv * 64;

    // stage W fragment tiles once: 64 KB linear gll16 copy (drained by the
    // first __syncthreads below)
    #pragma unroll
    for (int it = 0; it < 8; ++it) {
        int slot = it * 512 + tid;
        gll16(&Lw[slot * 8], &Wp[slot * 8]);
    }

    f32x4 acc[4][8] = {};

    for (int kc = 0; kc < 4; ++kc) {
        if (kc) __syncthreads();     // prior phase-B Yc reads / copy-out reads done
        // stage Xc: rows kc*128..+128, fp32 -> bf16, swizzled
        #pragma unroll
        for (int it = 0; it < 8; ++it) {
            int g = tid + it * 512;
            int r = g >> 5, c4 = g & 31;
            float4 v = *(const float4*)&X[(size_t)i * 65536 + (kc * 128 + r) * 128 + c4 * 4];
            int kb = c4 >> 4, c = c4 & 15, p = c >> 1, h2 = c & 1;
            bf16x4 pcv; pcv[0] = f2bf(v.x); pcv[1] = f2bf(v.y); pcv[2] = f2bf(v.z); pcv[3] = f2bf(v.w);
            *(bf16x4*)&Xc[kb * 8192 + r * 64 + ((p ^ (r & 7)) * 8 + h2 * 4)] = pcv;
        }
        __syncthreads();             // Xc (and on kc=0, Lw) visible

        // ---- phase A: quadrant (rowh,colh) of Xc @ W[mw], B-frags from Lw ----
        f32x4 ay[4][4] = {};
        #pragma unroll
        for (int sl = 0; sl < 4; ++sl) {
            int kb = sl >> 1, ks = sl & 1, Cc = ks * 4 + lq;
            int kt = kb * 2 + ks;
            bf16x8 af[4], bw[4];
            #pragma unroll
            for (int mf = 0; mf < 4; ++mf) {
                int R = rowh * 64 + mf * 16 + lm;
                af[mf] = *(const bf16x8*)&Xc[kb * 8192 + R * 64 + ((Cc ^ (R & 7)) * 8)];
            }
            #pragma unroll
            for (int nf = 0; nf < 4; ++nf)
                bw[nf] = *(const bf16x8*)&Lw[((mw * 8 + colh * 4 + nf) * 4 + kt) * 512 + lane * 8];
            #pragma unroll
            for (int mf = 0; mf < 4; ++mf)
                #pragma unroll
                for (int nf = 0; nf < 4; ++nf)
                    ay[mf][nf] = __builtin_amdgcn_mfma_f32_16x16x32_bf16(
                        af[mf], bw[nf], ay[mf][nf], 0, 0, 0);
        }
        __syncthreads();             // all Xc reads done -> Xc reusable as scratch

        if (mw == 0) {
            // Y1c quadrant -> Yc, n-major with the standard group swizzle
            #pragma unroll
            for (int mf = 0; mf < 4; ++mf)
                #pragma unroll
                for (int nf = 0; nf < 4; ++nf)
                    #pragma unroll
                    for (int rr = 0; rr < 4; ++rr) {
                        int rl64 = mf * 16 + lq * 4 + rr;          // k within 64-half
                        int n = colh * 64 + nf * 16 + lm;
                        Yc[rowh * 8192 + n * 64 + (((rl64 >> 3) ^ (n & 7)) * 8 + (rl64 & 7))]
                            = f2bf(ay[mf][nf][rr]);
                    }
        } else {
            // Y2c quadrant -> Xc scratch, natural [r][n]
            #pragma unroll
            for (int mf = 0; mf < 4; ++mf)
                #pragma unroll
                for (int nf = 0; nf < 4; ++nf)
                    #pragma unroll
                    for (int rr = 0; rr < 4; ++rr) {
                        int r = rowh * 64 + mf * 16 + lq * 4 + rr;
                        int n = colh * 64 + nf * 16 + lm;
                        Xc[r * 128 + n] = f2bf(ay[mf][nf][rr]);
                    }
        }
        __syncthreads();             // Yc + Y2 scratch complete

        // copy-out Y2 chunk: coalesced 16B stores (fire-and-forget)
        #pragma unroll
        for (int it = 0; it < 4; ++it) {
            int q = tid + it * 512;
            int row = q >> 4, oc = (q & 15) * 8;
            *(bf16x8*)&Y2[(size_t)i * 65536 + (kc * 128 + row) * 128 + oc]
                = *(const bf16x8*)&Xc[row * 128 + oc];
        }

        // ---- phase B: acc += At[wr..wr+64, kc*128..+128] @ Y1c ----
        #pragma unroll
        for (int kb2 = 0; kb2 < 2; ++kb2)
            #pragma unroll
            for (int ks = 0; ks < 2; ++ks) {
                int kt = kc * 4 + kb2 * 2 + ks;
                bf16x8 af[4], bf[8];
                #pragma unroll
                for (int mf = 0; mf < 4; ++mf)
                    af[mf] = *(const bf16x8*)&Atp[(size_t)((wv * 4 + mf) * 16 + kt) * 512 + lane * 8];
                #pragma unroll
                for (int nf = 0; nf < 8; ++nf) {
                    int R = nf * 16 + lm;
                    bf[nf] = *(const bf16x8*)&Yc[kb2 * 8192 + R * 64 + (((ks * 4 + lq) ^ (R & 7)) * 8)];
                }
                #pragma unroll
                for (int mf = 0; mf < 4; ++mf)
                    #pragma unroll
                    for (int nf = 0; nf < 8; ++nf)
                        acc[mf][nf] = __builtin_amdgcn_mfma_f32_16x16x32_bf16(
                            af[mf], bf[nf], acc[mf][nf], 0, 0, 0);
            }
    }

    // epilogue: partial[i] bf16, coalesced via LDS roundtrip in two half-passes
    // (uses the Xc+Yc 64 KB region as scratch; Lw dead)
    #pragma unroll
    for (int half = 0; half < 2; ++half) {
        __syncthreads();
        if ((wv >> 2) == half) {
            int lrb = (wv & 3) * 64;
            #pragma unroll
            for (int mf = 0; mf < 4; ++mf)
                #pragma unroll
                for (int nf = 0; nf < 8; ++nf)
                    #pragma unroll
                    for (int rr = 0; rr < 4; ++rr)
                        sh[(lrb + mf * 16 + lq * 4 + rr) * 128 + nf * 16 + lm]
                            = f2bf(acc[mf][nf][rr]);
        }
        __syncthreads();
        #pragma unroll
        for (int it = 0; it < 8; ++it) {
            int q = tid + it * 512;
            int row = q >> 4, oc = (q & 15) * 8;
            *(bf16x8*)&Pp[(size_t)i * 65536 + (half * 256 + row) * 128 + oc]
                = *(const bf16x8*)&sh[row * 128 + oc];
        }
    }
}

// ---------------- k_t: bf16 transpose Y2[k][j][n] -> Y2T[j][n][k] ----------------
__global__ __launch_bounds__(256) void k_t(const short* __restrict__ Y2,
                                           short* __restrict__ Y2T) {
    __shared__ __align__(16) u32 U[128 * 64];   // U[n][a]: (k=2a, 2a+1) packed
    const int tid = threadIdx.x;
    const int j  = blockIdx.x >> 2;
    const int k0 = (blockIdx.x & 3) * 128;

    const int c8 = tid & 15;         // 8-n chunk
    const int a0 = tid >> 4;         // pair index base
    #pragma unroll
    for (int it = 0; it < 4; ++it) {
        int a = a0 + it * 16;        // 0..63
        const short* r0 = &Y2[(size_t)(k0 + 2 * a) * 65536 + j * 128 + c8 * 8];
        bf16x8 A0 = *(const bf16x8*)r0;
        bf16x8 A1 = *(const bf16x8*)(r0 + 65536);
        #pragma unroll
        for (int cc = 0; cc < 8; ++cc) {
            int n = c8 * 8 + cc;
            U[n * 64 + (a ^ (n & 28))] =
                (u32)(unsigned short)A0[cc] | ((u32)(unsigned short)A1[cc] << 16);
        }
    }
    __syncthreads();
    const int ch = tid & 15;
    const int n0 = tid >> 4;
    #pragma unroll
    for (int it = 0; it < 8; ++it) {
        int n = n0 + it * 16;
        uint4 q = *(const uint4*)&U[n * 64 + ((ch * 4) ^ (n & 28))];
        *(uint4*)&Y2T[j * 65536 + n * 512 + k0 + ch * 8] = q;
    }
}

// ---------------- k_a2f: out = At@Y2T + X@W0 + partial + b ----------------
// block b: j = b>>2, i0 = (b&3)*128. At fragments read direct from packed Atp.
__global__ __launch_bounds__(256) void k_a2f(const float* __restrict__ X,
                                             const short* __restrict__ Atp,
                                             const short* __restrict__ Y2T,
                                             const short* __restrict__ Wt2,
                                             const short* __restrict__ Pp,
                                             const float* __restrict__ bias,
                                             float* __restrict__ out) {
    __shared__ __align__(16) short sm[16384];
    short* As = sm;
    short* Bs = sm + 8192;

    const int tid  = threadIdx.x;
    const int lane = tid & 63;
    const int wv   = tid >> 6;
    const int wr   = (wv >> 1) * 64;
    const int wc   = (wv & 1) * 64;
    const int lm   = lane & 15;
    const int lq   = lane >> 4;
    const int j  = blockIdx.x >> 2;
    const int i0 = (blockIdx.x & 3) * 128;

    f32x4 acc[4][4] = {};

    // ---- phase 1: X@W0, K=128 ----
    #pragma unroll
    for (int kb = 0; kb < 2; ++kb) {
        #pragma unroll
        for (int it = 0; it < 8; ++it) {
            int g = tid + it * 256;
            int r = g >> 4, c4 = g & 15;
            float4 v = *(const float4*)&X[(size_t)(i0 + r) * 65536 + j * 128 + kb * 64 + c4 * 4];
            int p = c4 >> 1, h2 = c4 & 1;
            bf16x4 pc; pc[0] = f2bf(v.x); pc[1] = f2bf(v.y); pc[2] = f2bf(v.z); pc[3] = f2bf(v.w);
            *(bf16x4*)&As[r * 64 + ((p ^ (r & 7)) * 8 + h2 * 4)] = pc;
        }
        #pragma unroll
        for (int it = 0; it < 4; ++it) {
            int slot = it * 256 + tid;
            int n = slot >> 3, pc = slot & 7;
            gll16(&Bs[slot * 8], &Wt2[n * 128 + kb * 64 + ((pc ^ (n & 7)) * 8)]);
        }
        __syncthreads();
        #pragma unroll
        for (int ks = 0; ks < 2; ++ks) {
            bf16x8 af[4], bf[4];
            #pragma unroll
            for (int mf = 0; mf < 4; ++mf) {
                int R = wr + mf * 16 + lm, Cc = ks * 4 + lq;
                af[mf] = *(const bf16x8*)&As[R * 64 + (Cc ^ (R & 7)) * 8];
            }
            #pragma unroll
            for (int nf = 0; nf < 4; ++nf) {
                int R = wc + nf * 16 + lm, Cc = ks * 4 + lq;
                bf[nf] = *(const bf16x8*)&Bs[R * 64 + (Cc ^ (R & 7)) * 8];
            }
            #pragma unroll
            for (int mf = 0; mf < 4; ++mf)
                #pragma unroll
                for (int nf = 0; nf < 4; ++nf)
                    acc[mf][nf] = __builtin_amdgcn_mfma_f32_16x16x32_bf16(
                        af[mf], bf[nf], acc[mf][nf], 0, 0, 0);
        }
        __syncthreads();
    }

    // ---- phase 2: At@Y2T, K=512; A-fragments direct from packed global ----
    const int jt0 = (i0 >> 4) + (wr >> 4);
    for (int kb = 0; kb < 8; ++kb) {
        const int k0 = kb * 64;
        #pragma unroll
        for (int it = 0; it < 4; ++it) {
            int slot = it * 256 + tid;
            int r = slot >> 3, p = slot & 7;
            int cg = (p ^ (r & 7)) * 8;
            gll16(&Bs[slot * 8], &Y2T[j * 65536 + r * 512 + k0 + cg]);
        }
        __syncthreads();
        #pragma unroll
        for (int ks = 0; ks < 2; ++ks) {
            int kt = kb * 2 + ks;
            bf16x8 af[4], bf[4];
            #pragma unroll
            for (int mf = 0; mf < 4; ++mf)
                af[mf] = *(const bf16x8*)&Atp[(size_t)((jt0 + mf) * 16 + kt) * 512 + lane * 8];
            #pragma unroll
            for (int nf = 0; nf < 4; ++nf) {
                int R = wc + nf * 16 + lm, Cc = ks * 4 + lq;
                bf[nf] = *(const bf16x8*)&Bs[R * 64 + (Cc ^ (R & 7)) * 8];
            }
            #pragma unroll
            for (int mf = 0; mf < 4; ++mf)
                #pragma unroll
                for (int nf = 0; nf < 4; ++nf)
                    acc[mf][nf] = __builtin_amdgcn_mfma_f32_16x16x32_bf16(
                        af[mf], bf[nf], acc[mf][nf], 0, 0, 0);
        }
        __syncthreads();
    }

    // ---- fused epilogue: + partial + bias -> fp32 out ----
    #pragma unroll
    for (int mf = 0; mf < 4; ++mf)
        #pragma unroll
        for (int nf = 0; nf < 4; ++nf)
            #pragma unroll
            for (int r = 0; r < 4; ++r)
                sm[(wr + mf * 16 + lq * 4 + r) * 128 + wc + nf * 16 + lm]
                    = f2bf(acc[mf][nf][r]);
    __syncthreads();
    #pragma unroll
    for (int it = 0; it < 8; ++it) {
        int q = tid + it * 256;
        int row = q >> 4, oc = (q & 15) * 8;
        bf16x8 vs = *(const bf16x8*)&sm[row * 128 + oc];
        bf16x8 vpl = *(const bf16x8*)&Pp[(size_t)(i0 + row) * 65536 + j * 128 + oc];
        float4 b0 = *(const float4*)&bias[oc];
        float4 b1 = *(const float4*)&bias[oc + 4];
        union { short s; __hip_bfloat16 h; } cs, cp;
        float o[8];
        #pragma unroll
        for (int e = 0; e < 8; ++e) {
            cs.s = vs[e]; cp.s = vpl[e];
            o[e] = __bfloat162float(cs.h) + __bfloat162float(cp.h);
        }
        o[0] += b0.x; o[1] += b0.y; o[2] += b0.z; o[3] += b0.w;
        o[4] += b1.x; o[5] += b1.y; o[6] += b1.z; o[7] += b1.w;
        float* op = &out[(size_t)(i0 + row) * 65536 + j * 128 + oc];
        float4 w0; w0.x = o[0]; w0.y = o[1]; w0.z = o[2]; w0.w = o[3];
        float4 w1; w1.x = o[4]; w1.y = o[5]; w1.z = o[6]; w1.w = o[7];
        *(float4*)op = w0;
        *(float4*)(op + 4) = w1;
    }
}

// ================= fallback path (round-1, proven, 130 MiB ws) =================

__global__ __launch_bounds__(256) void k_agg_fb(const float* __restrict__ X,
                                                const float* __restrict__ At,
                                                short* __restrict__ X1b,
                                                short* __restrict__ X2b) {
    __shared__ short As[128 * 72];
    __shared__ short Bs[128 * 72];
    const int tid  = threadIdx.x;
    const int lane = tid & 63;
    const int wv   = tid >> 6;
    const int wr   = (wv >> 1) * 64;
    const int wc   = (wv & 1) * 64;
    const int lm   = lane & 15;
    const int lq   = lane >> 4;
    int a0, Bbase, Bks, Cbase, Crs;
    short* Cp;
    const int bidx = blockIdx.x;
    if (bidx < 2048) {
        int i = bidx >> 2, jt = bidx & 3;
        a0 = jt * 128; Bbase = i * 65536; Bks = 128;
        Cbase = i * 65536 + jt * 16384; Crs = 128; Cp = X1b;
    } else {
        int bb = bidx - 2048;
        int j = bb >> 2, it = bb & 3;
        a0 = it * 128; Bbase = j * 128; Bks = 65536;
        Cbase = it * 8388608 + j * 128; Crs = 65536; Cp = X2b;
    }
    f32x4 acc[4][4] = {};
    const int d  = tid & 127;
    const int kh = tid >> 7;
    for (int kb = 0; kb < 8; ++kb) {
        const int k0 = kb * 64;
        #pragma unroll
        for (int it8 = 0; it8 < 8; ++it8) {
            int g = tid + it8 * 256;
            int r = g >> 4, kq = (g & 15) * 4;
            float4 v = *(const float4*)&At[(a0 + r) * 512 + k0 + kq];
            bf16x4 p; p[0] = f2bf(v.x); p[1] = f2bf(v.y); p[2] = f2bf(v.z); p[3] = f2bf(v.w);
            *(bf16x4*)&As[r * 72 + kq] = p;
        }
        #pragma unroll
        for (int gi = 0; gi < 4; ++gi) {
            int kg = kh * 4 + gi;
            bf16x8 p;
            #pragma unroll
            for (int jj = 0; jj < 8; ++jj)
                p[jj] = f2bf(X[Bbase + (k0 + kg * 8 + jj) * Bks + d]);
            *(bf16x8*)&Bs[d * 72 + kg * 8] = p;
        }
        __syncthreads();
        #pragma unroll
        for (int ks = 0; ks < 2; ++ks) {
            bf16x8 af[4], bfr[4];
            #pragma unroll
            for (int mf = 0; mf < 4; ++mf)
                af[mf] = *(const bf16x8*)&As[(wr + mf * 16 + lm) * 72 + ks * 32 + lq * 8];
            #pragma unroll
            for (int nf = 0; nf < 4; ++nf)
                bfr[nf] = *(const bf16x8*)&Bs[(wc + nf * 16 + lm) * 72 + ks * 32 + lq * 8];
            #pragma unroll
            for (int mf = 0; mf < 4; ++mf)
                #pragma unroll
                for (int nf = 0; nf < 4; ++nf)
                    acc[mf][nf] = __builtin_amdgcn_mfma_f32_16x16x32_bf16(
                        af[mf], bfr[nf], acc[mf][nf], 0, 0, 0);
        }
        __syncthreads();
    }
    #pragma unroll
    for (int mf = 0; mf < 4; ++mf)
        #pragma unroll
        for (int nf = 0; nf < 4; ++nf)
            #pragma unroll
            for (int r = 0; r < 4; ++r) {
                int row = wr + mf * 16 + lq * 4 + r;
                int col = wc + nf * 16 + lm;
                Cp[Cbase + row * Crs + col] = f2bf(acc[mf][nf][r]);
            }
}

__global__ __launch_bounds__(256) void k_final_fb(const float* __restrict__ X,
                                                  const short* __restrict__ X1b,
                                                  const short* __restrict__ X2b,
                                                  const short* __restrict__ Wt2,
                                                  const float* __restrict__ bias,
                                                  float* __restrict__ out) {
    __shared__ short As[128 * 72];
    __shared__ short Ws[128 * 72];
    const int tid  = threadIdx.x;
    const int lane = tid & 63;
    const int wv   = tid >> 6;
    const int wr   = (wv >> 1) * 64;
    const int wc   = (wv & 1) * 64;
    const int lm   = lane & 15;
    const int lq   = lane >> 4;
    const int m0   = blockIdx.x * 128;
    f32x4 acc[4][4] = {};
    for (int ph = 0; ph < 6; ++ph) {
        const int s = ph >> 1, h = ph & 1;
        if (s == 0) {
            #pragma unroll
            for (int it8 = 0; it8 < 8; ++it8) {
                int g = tid + it8 * 256;
                int r = g >> 4, kq = (g & 15) * 4;
                float4 v = *(const float4*)&X[(m0 + r) * 128 + h * 64 + kq];
                bf16x4 p; p[0] = f2bf(v.x); p[1] = f2bf(v.y); p[2] = f2bf(v.z); p[3] = f2bf(v.w);
                *(bf16x4*)&As[r * 72 + kq] = p;
            }
        } else {
            const short* src = (s == 1) ? X1b : X2b;
            #pragma unroll
            for (int it4 = 0; it4 < 4; ++it4) {
                int g = tid + it4 * 256;
                int r = g >> 3, ko = (g & 7) * 8;
                *(bf16x8*)&As[r * 72 + ko] =
                    *(const bf16x8*)&src[(m0 + r) * 128 + h * 64 + ko];
            }
        }
        #pragma unroll
        for (int it4 = 0; it4 < 4; ++it4) {
            int g = tid + it4 * 256;
            int n = g >> 3, ko = (g & 7) * 8;
            *(bf16x8*)&Ws[n * 72 + ko] =
                *(const bf16x8*)&Wt2[s * 16384 + n * 128 + h * 64 + ko];
        }
        __syncthreads();
        #pragma unroll
        for (int ks = 0; ks < 2; ++ks) {
            bf16x8 af[4], bfr[4];
            #pragma unroll
            for (int mf = 0; mf < 4; ++mf)
                af[mf] = *(const bf16x8*)&As[(wr + mf * 16 + lm) * 72 + ks * 32 + lq * 8];
            #pragma unroll
            for (int nf = 0; nf < 4; ++nf)
                bfr[nf] = *(const bf16x8*)&Ws[(wc + nf * 16 + lm) * 72 + ks * 32 + lq * 8];
            #pragma unroll
            for (int mf = 0; mf < 4; ++mf)
                #pragma unroll
                for (int nf = 0; nf < 4; ++nf)
                    acc[mf][nf] = __builtin_amdgcn_mfma_f32_16x16x32_bf16(
                        af[mf], bfr[nf], acc[mf][nf], 0, 0, 0);
        }
        __syncthreads();
    }
    #pragma unroll
    for (int nf = 0; nf < 4; ++nf) {
        float bv = bias[wc + nf * 16 + lm];
        #pragma unroll
        for (int mf = 0; mf < 4; ++mf)
            #pragma unroll
            for (int r = 0; r < 4; ++r) {
                int row = m0 + wr + mf * 16 + lq * 4 + r;
                int col = wc + nf * 16 + lm;
                out[row * 128 + col] = acc[mf][nf][r] + bv;
            }
    }
}

extern "C" void kernel_launch(void* const* d_in, const int* in_sizes, int n_in,
                              void* d_out, int out_size, void* d_ws, size_t ws_size,
                              hipStream_t stream) {
    const float* X  = (const float*)d_in[0];
    const int*   ei = (const int*)d_in[1];
    const float* W  = (const float*)d_in[2];
    const float* b  = (const float*)d_in[3];
    float* out = (float*)d_out;
    char* ws = (char*)d_ws;
    const size_t MB = 1u << 20;

    float* At  = (float*)ws;                            // [0, 1M)
    short* Atp = (short*)(ws + 1 * MB);                 // [1M, 1.5M) packed A-frag
    short* Wt2 = (short*)(ws + 1 * MB + 512 * 1024);    // 96 KiB
    short* Wp  = (short*)(ws + 1 * MB + 640 * 1024);    // 64 KiB packed B-frag W1/W2

    k_zero   <<<1024, 256, 0, stream>>>(At);
    k_edges  <<<1, 1024, 0, stream>>>(ei, At);
    k_wt2    <<<192, 256, 0, stream>>>(W, Wt2);
    k_pack_at<<<128, 256, 0, stream>>>(At, Atp);
    k_pack_w <<<16, 256, 0, stream>>>(W, Wp);

    if (ws_size >= 194 * MB) {
        short* Y2  = (short*)(ws + 2 * MB);     // 64M: X@W2, natural [k][j][n]
        short* Y2T = (short*)(ws + 66 * MB);    // 64M: transposed [j][n][k]
        short* Pp  = (short*)(ws + 130 * MB);   // 64M: partial = At@(X@W1)
        k_slab<<<512, 512, 0, stream>>>(X, Wp, Atp, Y2, Pp);
        k_t   <<<2048, 256, 0, stream>>>(Y2, Y2T);
        k_a2f <<<2048, 256, 0, stream>>>(X, Atp, Y2T, Wt2, Pp, b, out);
    } else {
        short* X1b = (short*)(ws + 2 * MB);
        short* X2b = (short*)(ws + 66 * MB);
        k_agg_fb  <<<4096, 256, 0, stream>>>(X, At, X1b, X2b);
        k_final_fb<<<2048, 256, 0, stream>>>(X, X1b, X2b, Wt2, b, out);
    }
}

// Round 4
// 492.076 us; speedup vs baseline: 1.1618x; 1.0948x over previous
//
#include <hip/hip_runtime.h>
#include <hip/hip_bf16.h>
#include <stdint.h>

// Sizes (fixed by the problem)
#define NN 512
#define DD 128
#define EE 16384

typedef short bf16x8 __attribute__((ext_vector_type(8)));
typedef short bf16x4 __attribute__((ext_vector_type(4)));
typedef float f32x4  __attribute__((ext_vector_type(4)));
typedef unsigned int u32;

__device__ __forceinline__ short f2bf(float f) {
    union { __hip_bfloat16 h; short s; } u;
    u.h = __float2bfloat16(f);
    return u.s;
}
__device__ __forceinline__ u32 pk2(float a, float b) {
    return (u32)(unsigned short)f2bf(a) | ((u32)(unsigned short)f2bf(b) << 16);
}

// async global->LDS 16B copy. LDS dest = wave-uniform base + lane*16 (linear in
// tid); XOR swizzle is applied on the SOURCE chunk index.
typedef __attribute__((address_space(3))) unsigned int lds_u32;
typedef __attribute__((address_space(1))) const unsigned int glb_u32;
__device__ __forceinline__ void gll16(void* l, const void* g) {
    __builtin_amdgcn_global_load_lds((glb_u32*)g, (lds_u32*)l, 16, 0, 0);
}

// ---------------- tiny prep kernels ----------------

__global__ void k_zero(float* __restrict__ At) {
    At[blockIdx.x * 256 + threadIdx.x] = 0.0f;
}

// Build At[dst][src] += 1.  Robust to int32 or int64 input (for int64 LE every
// odd 32-bit word is 0 since values < 512).
__global__ void k_edges(const int* __restrict__ ei, float* __restrict__ At) {
    __shared__ int flag;
    if (threadIdx.x == 0) flag = 0;
    __syncthreads();
    int any = 0;
    for (int i = threadIdx.x; i < EE; i += blockDim.x) any |= ei[2 * i + 1];
    if (any) atomicOr(&flag, 1);
    __syncthreads();
    const bool is32 = (flag != 0);
    for (int e = threadIdx.x; e < EE; e += blockDim.x) {
        int src, dst;
        if (is32) { src = ei[e];     dst = ei[EE + e]; }
        else      { src = ei[2 * e]; dst = ei[2 * (EE + e)]; }
        atomicAdd(&At[dst * NN + src], 1.0f);
    }
}

// Wt2[s][n][d] = bf16(W[(s*128+d)*128 + n])
__global__ void k_wt2(const float* __restrict__ W, short* __restrict__ Wt2) {
    int t = blockIdx.x * 256 + threadIdx.x;     // t = kk*128 + n, kk = s*128+d
    int kk = t >> 7, n = t & 127;
    int s = kk >> 7, d = kk & 127;
    Wt2[s * 16384 + n * 128 + d] = f2bf(W[t]);
}

// Pack At into MFMA A-fragment tile order: tile T = jt*16 + kt covers rows
// jt*16..+16, cols kt*32..+32; lane l holds At[jt*16 + (l&15)][kt*32 + (l>>4)*8 + e].
// A wave's fragment load is 64 lanes x 16B contiguous (1 KB), L2-resident.
__global__ void k_pack_at(const float* __restrict__ At, short* __restrict__ Atp) {
    int t = blockIdx.x * 256 + threadIdx.x;     // 32768 threads
    int T = t >> 6, l = t & 63;
    int row = (T >> 4) * 16 + (l & 15);
    int col = (T & 15) * 32 + (l >> 4) * 8;
    const float* s = &At[row * 512 + col];
    bf16x8 p;
    #pragma unroll
    for (int e = 0; e < 8; ++e) p[e] = f2bf(s[e]);
    *(bf16x8*)&Atp[(size_t)T * 512 + l * 8] = p;
}

// ---------------- k_y: Y1T / Y2 from one pass over X (round-0, proven) --------
// block b: i = b>>2, j0 = (b&3)*128; rows m = (i, j0+r).
// Y1T[i][n][j] = bf16( sum_d X[i][j][d] W1[d][n] )   (transposed in epilogue)
// Y2 [i][j][n] = bf16( sum_d X[i][j][d] W2[d][n] )   (natural)
__global__ __launch_bounds__(256) void k_y(const float* __restrict__ X,
                                           const short* __restrict__ Wt2,
                                           short* __restrict__ Y1T,
                                           short* __restrict__ Y2) {
    __shared__ __align__(16) short Xs[16384];   // [kb][r][64 swizzled]
    __shared__ __align__(16) short Ws[16384];   // [kb][n][64 swizzled]; epilogue scratch

    const int tid  = threadIdx.x;
    const int lane = tid & 63;
    const int wv   = tid >> 6;
    const int wr   = (wv >> 1) * 64;
    const int wc   = (wv & 1) * 64;
    const int lm   = lane & 15;
    const int lq   = lane >> 4;
    const int i  = blockIdx.x >> 2;
    const int j0 = (blockIdx.x & 3) * 128;

    // stage X tile once: fp32 -> bf16, contiguous 64 KB region, coalesced
    #pragma unroll
    for (int it = 0; it < 16; ++it) {
        int g = tid + it * 256;
        int r = g >> 5, c4 = g & 31;
        float4 v = *(const float4*)&X[i * 65536 + (j0 + r) * 128 + c4 * 4];
        int kb = c4 >> 4, c = c4 & 15, p = c >> 1, h2 = c & 1;
        bf16x4 pc; pc[0] = f2bf(v.x); pc[1] = f2bf(v.y); pc[2] = f2bf(v.z); pc[3] = f2bf(v.w);
        *(bf16x4*)&Xs[kb * 8192 + r * 64 + ((p ^ (r & 7)) * 8 + h2 * 4)] = pc;
    }

    #pragma unroll
    for (int s = 1; s <= 2; ++s) {
        // stage W[s] (both kb halves): dest linear, src chunk XOR-swizzled
        #pragma unroll
        for (int it = 0; it < 8; ++it) {
            int slot = it * 256 + tid;              // = kb*1024 + n*8 + pc
            int kb = slot >> 10, rem = slot & 1023;
            int n = rem >> 3, pc = rem & 7;
            gll16(&Ws[slot * 8],
                  &Wt2[s * 16384 + n * 128 + kb * 64 + ((pc ^ (n & 7)) * 8)]);
        }
        __syncthreads();

        f32x4 acc[4][4] = {};
        #pragma unroll
        for (int kb = 0; kb < 2; ++kb)
            #pragma unroll
            for (int ks = 0; ks < 2; ++ks) {
                bf16x8 af[4], bf[4];
                #pragma unroll
                for (int mf = 0; mf < 4; ++mf) {
                    int R = wr + mf * 16 + lm, Cc = ks * 4 + lq;
                    af[mf] = *(const bf16x8*)&Xs[kb * 8192 + R * 64 + (Cc ^ (R & 7)) * 8];
                }
                #pragma unroll
                for (int nf = 0; nf < 4; ++nf) {
                    int R = wc + nf * 16 + lm, Cc = ks * 4 + lq;
                    bf[nf] = *(const bf16x8*)&Ws[kb * 8192 + R * 64 + (Cc ^ (R & 7)) * 8];
                }
                #pragma unroll
                for (int mf = 0; mf < 4; ++mf)
                    #pragma unroll
                    for (int nf = 0; nf < 4; ++nf)
                        acc[mf][nf] = __builtin_amdgcn_mfma_f32_16x16x32_bf16(
                            af[mf], bf[nf], acc[mf][nf], 0, 0, 0);
            }
        __syncthreads();   // MFMA reads of Ws done -> safe to reuse as scratch

        if (s == 1) {
            // transposed epilogue: T[n][j] u32-pairs, XOR-swizzled, b64 writes
            u32* T = (u32*)Ws;
            #pragma unroll
            for (int mf = 0; mf < 4; ++mf)
                #pragma unroll
                for (int nf = 0; nf < 4; ++nf) {
                    int n = wc + nf * 16 + lm;
                    int jb = wr + mf * 16 + lq * 4;   // multiple of 4
                    int w = jb >> 1;                   // even
                    u32 lo = pk2(acc[mf][nf][0], acc[mf][nf][1]);
                    u32 hi = pk2(acc[mf][nf][2], acc[mf][nf][3]);
                    uint2 val; val.x = lo; val.y = hi;
                    *(uint2*)&T[n * 64 + (w ^ (n & 28))] = val;
                }
            __syncthreads();
            #pragma unroll
            for (int it = 0; it < 8; ++it) {
                int ch = tid & 15, n = (tid >> 4) + it * 16;
                uint4 q = *(const uint4*)&T[n * 64 + ((ch * 4) ^ (n & 28))];
                *(uint4*)&Y1T[i * 65536 + n * 512 + j0 + ch * 8] = q;
            }
            __syncthreads();   // before s=2 W staging overwrites T
        } else {
            // natural epilogue via LDS round-trip -> coalesced 16B stores
            #pragma unroll
            for (int mf = 0; mf < 4; ++mf)
                #pragma unroll
                for (int nf = 0; nf < 4; ++nf)
                    #pragma unroll
                    for (int r = 0; r < 4; ++r)
                        Ws[(wr + mf * 16 + lq * 4 + r) * 128 + wc + nf * 16 + lm]
                            = f2bf(acc[mf][nf][r]);
            __syncthreads();
            #pragma unroll
            for (int it = 0; it < 8; ++it) {
                int q = tid + it * 256;
                int row = q >> 4, oc = (q & 15) * 8;
                *(bf16x8*)&Y2[i * 65536 + (j0 + row) * 128 + oc]
                    = *(const bf16x8*)&Ws[row * 128 + oc];
            }
        }
    }
}

// ---------------- k_t: bf16 transpose Y2[k][j][n] -> Y2T[j][n][k] ----------------
// XCD-chunked swizzle: consecutive logical j-groups stay on one XCD.
__global__ __launch_bounds__(256) void k_t(const short* __restrict__ Y2,
                                           short* __restrict__ Y2T) {
    __shared__ __align__(16) u32 U[128 * 64];   // U[n][a]: (k=2a, 2a+1) packed
    const int tid = threadIdx.x;
    const int bid = (blockIdx.x & 7) * 256 + (blockIdx.x >> 3);   // 2048 % 8 == 0
    const int j  = bid >> 2;
    const int k0 = (bid & 3) * 128;

    const int c8 = tid & 15;         // 8-n chunk
    const int a0 = tid >> 4;         // pair index base
    #pragma unroll
    for (int it = 0; it < 4; ++it) {
        int a = a0 + it * 16;        // 0..63
        const short* r0 = &Y2[(size_t)(k0 + 2 * a) * 65536 + j * 128 + c8 * 8];
        bf16x8 A0 = *(const bf16x8*)r0;
        bf16x8 A1 = *(const bf16x8*)(r0 + 65536);
        #pragma unroll
        for (int cc = 0; cc < 8; ++cc) {
            int n = c8 * 8 + cc;
            U[n * 64 + (a ^ (n & 28))] =
                (u32)(unsigned short)A0[cc] | ((u32)(unsigned short)A1[cc] << 16);
        }
    }
    __syncthreads();
    const int ch = tid & 15;
    const int n0 = tid >> 4;
    #pragma unroll
    for (int it = 0; it < 8; ++it) {
        int n = n0 + it * 16;
        uint4 q = *(const uint4*)&U[n * 64 + ((ch * 4) ^ (n & 28))];
        *(uint4*)&Y2T[j * 65536 + n * 512 + k0 + ch * 8] = q;
    }
}

// ---------------- k_a1: P1[i][j][n] = sum_k At[j,k] Y1T[i][n][k] ----------------
// A-fragments direct from packed Atp (L2); B double-buffered with prefetch
// issued before compute (2-phase); one barrier per K-step. XCD swizzle keeps
// the 4 blocks sharing Y1T[i] on one XCD.
__global__ __launch_bounds__(256) void k_a1(const short* __restrict__ Atp,
                                            const short* __restrict__ Y1T,
                                            short* __restrict__ P1) {
    __shared__ __align__(16) short sm[16384];   // two 16 KB B buffers

    const int tid  = threadIdx.x;
    const int lane = tid & 63;
    const int wv   = tid >> 6;
    const int wr   = (wv >> 1) * 64;
    const int wc   = (wv & 1) * 64;
    const int lm   = lane & 15;
    const int lq   = lane >> 4;
    const int bid = (blockIdx.x & 7) * 256 + (blockIdx.x >> 3);
    const int i  = bid >> 2;
    const int a0 = (bid & 3) * 128;
    const int jt0 = (a0 >> 4) + (wr >> 4);

    f32x4 acc[4][4] = {};

    // prologue: stage kb=0 into buffer 0
    #pragma unroll
    for (int it = 0; it < 4; ++it) {
        int slot = it * 256 + tid;
        int r = slot >> 3, p = slot & 7;
        int cg = (p ^ (r & 7)) * 8;
        gll16(&sm[slot * 8], &Y1T[i * 65536 + r * 512 + cg]);
    }
    __syncthreads();

    for (int kb = 0; kb < 8; ++kb) {
        short* cur = (kb & 1) ? sm + 8192 : sm;
        short* nxt = (kb & 1) ? sm : sm + 8192;
        if (kb < 7) {
            const int k0n = (kb + 1) * 64;
            #pragma unroll
            for (int it = 0; it < 4; ++it) {
                int slot = it * 256 + tid;
                int r = slot >> 3, p = slot & 7;
                int cg = (p ^ (r & 7)) * 8;
                gll16(&nxt[slot * 8], &Y1T[i * 65536 + r * 512 + k0n + cg]);
            }
        }
        #pragma unroll
        for (int ks = 0; ks < 2; ++ks) {
            int kt = kb * 2 + ks;
            bf16x8 af[4], bf[4];
            #pragma unroll
            for (int mf = 0; mf < 4; ++mf)
                af[mf] = *(const bf16x8*)&Atp[(size_t)((jt0 + mf) * 16 + kt) * 512 + lane * 8];
            #pragma unroll
            for (int nf = 0; nf < 4; ++nf) {
                int R = wc + nf * 16 + lm, Cc = ks * 4 + lq;
                bf[nf] = *(const bf16x8*)&cur[R * 64 + (Cc ^ (R & 7)) * 8];
            }
            #pragma unroll
            for (int mf = 0; mf < 4; ++mf)
                #pragma unroll
                for (int nf = 0; nf < 4; ++nf)
                    acc[mf][nf] = __builtin_amdgcn_mfma_f32_16x16x32_bf16(
                        af[mf], bf[nf], acc[mf][nf], 0, 0, 0);
        }
        __syncthreads();   // drains nxt prefetch; orders buffer reuse
    }

    // epilogue: coalesced via LDS round-trip
    #pragma unroll
    for (int mf = 0; mf < 4; ++mf)
        #pragma unroll
        for (int nf = 0; nf < 4; ++nf)
            #pragma unroll
            for (int r = 0; r < 4; ++r)
                sm[(wr + mf * 16 + lq * 4 + r) * 128 + wc + nf * 16 + lm]
                    = f2bf(acc[mf][nf][r]);
    __syncthreads();
    #pragma unroll
    for (int it = 0; it < 8; ++it) {
        int q = tid + it * 256;
        int row = q >> 4, oc = (q & 15) * 8;
        *(bf16x8*)&P1[i * 65536 + (a0 + row) * 128 + oc]
            = *(const bf16x8*)&sm[row * 128 + oc];
    }
}

// ---------------- k_a2f: out = At@Y2T + X@W0 + P1 + b ----------------
// block: j = bid>>2, i0 = (bid&3)*128. Phase 2 double-buffered with Atp-direct
// A-fragments; XCD swizzle keeps the 4 blocks sharing Y2T[j] on one XCD.
__global__ __launch_bounds__(256) void k_a2f(const float* __restrict__ X,
                                             const short* __restrict__ Atp,
                                             const short* __restrict__ Y2T,
                                             const short* __restrict__ Wt2,
                                             const short* __restrict__ P1,
                                             const float* __restrict__ bias,
                                             float* __restrict__ out) {
    __shared__ __align__(16) short sm[16384];
    short* As = sm;
    short* Bs = sm + 8192;

    const int tid  = threadIdx.x;
    const int lane = tid & 63;
    const int wv   = tid >> 6;
    const int wr   = (wv >> 1) * 64;
    const int wc   = (wv & 1) * 64;
    const int lm   = lane & 15;
    const int lq   = lane >> 4;
    const int bid = (blockIdx.x & 7) * 256 + (blockIdx.x >> 3);
    const int j  = bid >> 2;
    const int i0 = (bid & 3) * 128;

    f32x4 acc[4][4] = {};

    // ---- phase 1: X@W0, K=128 ----
    #pragma unroll
    for (int kb = 0; kb < 2; ++kb) {
        #pragma unroll
        for (int it = 0; it < 8; ++it) {
            int g = tid + it * 256;
            int r = g >> 4, c4 = g & 15;
            float4 v = *(const float4*)&X[(size_t)(i0 + r) * 65536 + j * 128 + kb * 64 + c4 * 4];
            int p = c4 >> 1, h2 = c4 & 1;
            bf16x4 pc; pc[0] = f2bf(v.x); pc[1] = f2bf(v.y); pc[2] = f2bf(v.z); pc[3] = f2bf(v.w);
            *(bf16x4*)&As[r * 64 + ((p ^ (r & 7)) * 8 + h2 * 4)] = pc;
        }
        #pragma unroll
        for (int it = 0; it < 4; ++it) {
            int slot = it * 256 + tid;
            int n = slot >> 3, pc = slot & 7;
            gll16(&Bs[slot * 8], &Wt2[n * 128 + kb * 64 + ((pc ^ (n & 7)) * 8)]);
        }
        __syncthreads();
        #pragma unroll
        for (int ks = 0; ks < 2; ++ks) {
            bf16x8 af[4], bf[4];
            #pragma unroll
            for (int mf = 0; mf < 4; ++mf) {
                int R = wr + mf * 16 + lm, Cc = ks * 4 + lq;
                af[mf] = *(const bf16x8*)&As[R * 64 + (Cc ^ (R & 7)) * 8];
            }
            #pragma unroll
            for (int nf = 0; nf < 4; ++nf) {
                int R = wc + nf * 16 + lm, Cc = ks * 4 + lq;
                bf[nf] = *(const bf16x8*)&Bs[R * 64 + (Cc ^ (R & 7)) * 8];
            }
            #pragma unroll
            for (int mf = 0; mf < 4; ++mf)
                #pragma unroll
                for (int nf = 0; nf < 4; ++nf)
                    acc[mf][nf] = __builtin_amdgcn_mfma_f32_16x16x32_bf16(
                        af[mf], bf[nf], acc[mf][nf], 0, 0, 0);
        }
        __syncthreads();
    }

    // ---- phase 2: At@Y2T, K=512; double-buffered B, Atp-direct A ----
    const int jt0 = (i0 >> 4) + (wr >> 4);
    // prologue: stage kb=0 into buffer 0 (As region, dead after phase 1)
    #pragma unroll
    for (int it = 0; it < 4; ++it) {
        int slot = it * 256 + tid;
        int r = slot >> 3, p = slot & 7;
        int cg = (p ^ (r & 7)) * 8;
        gll16(&sm[slot * 8], &Y2T[j * 65536 + r * 512 + cg]);
    }
    __syncthreads();

    for (int kb = 0; kb < 8; ++kb) {
        short* cur = (kb & 1) ? sm + 8192 : sm;
        short* nxt = (kb & 1) ? sm : sm + 8192;
        if (kb < 7) {
            const int k0n = (kb + 1) * 64;
            #pragma unroll
            for (int it = 0; it < 4; ++it) {
                int slot = it * 256 + tid;
                int r = slot >> 3, p = slot & 7;
                int cg = (p ^ (r & 7)) * 8;
                gll16(&nxt[slot * 8], &Y2T[j * 65536 + r * 512 + k0n + cg]);
            }
        }
        #pragma unroll
        for (int ks = 0; ks < 2; ++ks) {
            int kt = kb * 2 + ks;
            bf16x8 af[4], bf[4];
            #pragma unroll
            for (int mf = 0; mf < 4; ++mf)
                af[mf] = *(const bf16x8*)&Atp[(size_t)((jt0 + mf) * 16 + kt) * 512 + lane * 8];
            #pragma unroll
            for (int nf = 0; nf < 4; ++nf) {
                int R = wc + nf * 16 + lm, Cc = ks * 4 + lq;
                bf[nf] = *(const bf16x8*)&cur[R * 64 + (Cc ^ (R & 7)) * 8];
            }
            #pragma unroll
            for (int mf = 0; mf < 4; ++mf)
                #pragma unroll
                for (int nf = 0; nf < 4; ++nf)
                    acc[mf][nf] = __builtin_amdgcn_mfma_f32_16x16x32_bf16(
                        af[mf], bf[nf], acc[mf][nf], 0, 0, 0);
        }
        __syncthreads();
    }

    // ---- fused epilogue: + P1 + bias -> fp32 out ----
    #pragma unroll
    for (int mf = 0; mf < 4; ++mf)
        #pragma unroll
        for (int nf = 0; nf < 4; ++nf)
            #pragma unroll
            for (int r = 0; r < 4; ++r)
                sm[(wr + mf * 16 + lq * 4 + r) * 128 + wc + nf * 16 + lm]
                    = f2bf(acc[mf][nf][r]);
    __syncthreads();
    #pragma unroll
    for (int it = 0; it < 8; ++it) {
        int q = tid + it * 256;
        int row = q >> 4, oc = (q & 15) * 8;
        bf16x8 vs = *(const bf16x8*)&sm[row * 128 + oc];
        bf16x8 vpl = *(const bf16x8*)&P1[(size_t)(i0 + row) * 65536 + j * 128 + oc];
        float4 b0 = *(const float4*)&bias[oc];
        float4 b1 = *(const float4*)&bias[oc + 4];
        union { short s; __hip_bfloat16 h; } cs, cp;
        float o[8];
        #pragma unroll
        for (int e = 0; e < 8; ++e) {
            cs.s = vs[e]; cp.s = vpl[e];
            o[e] = __bfloat162float(cs.h) + __bfloat162float(cp.h);
        }
        o[0] += b0.x; o[1] += b0.y; o[2] += b0.z; o[3] += b0.w;
        o[4] += b1.x; o[5] += b1.y; o[6] += b1.z; o[7] += b1.w;
        float* op = &out[(size_t)(i0 + row) * 65536 + j * 128 + oc];
        float4 w0; w0.x = o[0]; w0.y = o[1]; w0.z = o[2]; w0.w = o[3];
        float4 w1; w1.x = o[4]; w1.y = o[5]; w1.z = o[6]; w1.w = o[7];
        *(float4*)op = w0;
        *(float4*)(op + 4) = w1;
    }
}

// ================= fallback path (round-1, proven, 130 MiB ws) =================

__global__ __launch_bounds__(256) void k_agg_fb(const float* __restrict__ X,
                                                const float* __restrict__ At,
                                                short* __restrict__ X1b,
                                                short* __restrict__ X2b) {
    __shared__ short As[128 * 72];
    __shared__ short Bs[128 * 72];
    const int tid  = threadIdx.x;
    const int lane = tid & 63;
    const int wv   = tid >> 6;
    const int wr   = (wv >> 1) * 64;
    const int wc   = (wv & 1) * 64;
    const int lm   = lane & 15;
    const int lq   = lane >> 4;
    int a0, Bbase, Bks, Cbase, Crs;
    short* Cp;
    const int bidx = blockIdx.x;
    if (bidx < 2048) {
        int i = bidx >> 2, jt = bidx & 3;
        a0 = jt * 128; Bbase = i * 65536; Bks = 128;
        Cbase = i * 65536 + jt * 16384; Crs = 128; Cp = X1b;
    } else {
        int bb = bidx - 2048;
        int j = bb >> 2, it = bb & 3;
        a0 = it * 128; Bbase = j * 128; Bks = 65536;
        Cbase = it * 8388608 + j * 128; Crs = 65536; Cp = X2b;
    }
    f32x4 acc[4][4] = {};
    const int d  = tid & 127;
    const int kh = tid >> 7;
    for (int kb = 0; kb < 8; ++kb) {
        const int k0 = kb * 64;
        #pragma unroll
        for (int it8 = 0; it8 < 8; ++it8) {
            int g = tid + it8 * 256;
            int r = g >> 4, kq = (g & 15) * 4;
            float4 v = *(const float4*)&At[(a0 + r) * 512 + k0 + kq];
            bf16x4 p; p[0] = f2bf(v.x); p[1] = f2bf(v.y); p[2] = f2bf(v.z); p[3] = f2bf(v.w);
            *(bf16x4*)&As[r * 72 + kq] = p;
        }
        #pragma unroll
        for (int gi = 0; gi < 4; ++gi) {
            int kg = kh * 4 + gi;
            bf16x8 p;
            #pragma unroll
            for (int jj = 0; jj < 8; ++jj)
                p[jj] = f2bf(X[Bbase + (k0 + kg * 8 + jj) * Bks + d]);
            *(bf16x8*)&Bs[d * 72 + kg * 8] = p;
        }
        __syncthreads();
        #pragma unroll
        for (int ks = 0; ks < 2; ++ks) {
            bf16x8 af[4], bfr[4];
            #pragma unroll
            for (int mf = 0; mf < 4; ++mf)
                af[mf] = *(const bf16x8*)&As[(wr + mf * 16 + lm) * 72 + ks * 32 + lq * 8];
            #pragma unroll
            for (int nf = 0; nf < 4; ++nf)
                bfr[nf] = *(const bf16x8*)&Bs[(wc + nf * 16 + lm) * 72 + ks * 32 + lq * 8];
            #pragma unroll
            for (int mf = 0; mf < 4; ++mf)
                #pragma unroll
                for (int nf = 0; nf < 4; ++nf)
                    acc[mf][nf] = __builtin_amdgcn_mfma_f32_16x16x32_bf16(
                        af[mf], bfr[nf], acc[mf][nf], 0, 0, 0);
        }
        __syncthreads();
    }
    #pragma unroll
    for (int mf = 0; mf < 4; ++mf)
        #pragma unroll
        for (int nf = 0; nf < 4; ++nf)
            #pragma unroll
            for (int r = 0; r < 4; ++r) {
                int row = wr + mf * 16 + lq * 4 + r;
                int col = wc + nf * 16 + lm;
                Cp[Cbase + row * Crs + col] = f2bf(acc[mf][nf][r]);
            }
}

__global__ __launch_bounds__(256) void k_final_fb(const float* __restrict__ X,
                                                  const short* __restrict__ X1b,
                                                  const short* __restrict__ X2b,
                                                  const short* __restrict__ Wt2,
                                                  const float* __restrict__ bias,
                                                  float* __restrict__ out) {
    __shared__ short As[128 * 72];
    __shared__ short Ws[128 * 72];
    const int tid  = threadIdx.x;
    const int lane = tid & 63;
    const int wv   = tid >> 6;
    const int wr   = (wv >> 1) * 64;
    const int wc   = (wv & 1) * 64;
    const int lm   = lane & 15;
    const int lq   = lane >> 4;
    const int m0   = blockIdx.x * 128;
    f32x4 acc[4][4] = {};
    for (int ph = 0; ph < 6; ++ph) {
        const int s = ph >> 1, h = ph & 1;
        if (s == 0) {
            #pragma unroll
            for (int it8 = 0; it8 < 8; ++it8) {
                int g = tid + it8 * 256;
                int r = g >> 4, kq = (g & 15) * 4;
                float4 v = *(const float4*)&X[(m0 + r) * 128 + h * 64 + kq];
                bf16x4 p; p[0] = f2bf(v.x); p[1] = f2bf(v.y); p[2] = f2bf(v.z); p[3] = f2bf(v.w);
                *(bf16x4*)&As[r * 72 + kq] = p;
            }
        } else {
            const short* src = (s == 1) ? X1b : X2b;
            #pragma unroll
            for (int it4 = 0; it4 < 4; ++it4) {
                int g = tid + it4 * 256;
                int r = g >> 3, ko = (g & 7) * 8;
                *(bf16x8*)&As[r * 72 + ko] =
                    *(const bf16x8*)&src[(m0 + r) * 128 + h * 64 + ko];
            }
        }
        #pragma unroll
        for (int it4 = 0; it4 < 4; ++it4) {
            int g = tid + it4 * 256;
            int n = g >> 3, ko = (g & 7) * 8;
            *(bf16x8*)&Ws[n * 72 + ko] =
                *(const bf16x8*)&Wt2[s * 16384 + n * 128 + h * 64 + ko];
        }
        __syncthreads();
        #pragma unroll
        for (int ks = 0; ks < 2; ++ks) {
            bf16x8 af[4], bfr[4];
            #pragma unroll
            for (int mf = 0; mf < 4; ++mf)
                af[mf] = *(const bf16x8*)&As[(wr + mf * 16 + lm) * 72 + ks * 32 + lq * 8];
            #pragma unroll
            for (int nf = 0; nf < 4; ++nf)
                bfr[nf] = *(const bf16x8*)&Ws[(wc + nf * 16 + lm) * 72 + ks * 32 + lq * 8];
            #pragma unroll
            for (int mf = 0; mf < 4; ++mf)
                #pragma unroll
                for (int nf = 0; nf < 4; ++nf)
                    acc[mf][nf] = __builtin_amdgcn_mfma_f32_16x16x32_bf16(
                        af[mf], bfr[nf], acc[mf][nf], 0, 0, 0);
        }
        __syncthreads();
    }
    #pragma unroll
    for (int nf = 0; nf < 4; ++nf) {
        float bv = bias[wc + nf * 16 + lm];
        #pragma unroll
        for (int mf = 0; mf < 4; ++mf)
            #pragma unroll
            for (int r = 0; r < 4; ++r) {
                int row = m0 + wr + mf * 16 + lq * 4 + r;
                int col = wc + nf * 16 + lm;
                out[row * 128 + col] = acc[mf][nf][r] + bv;
            }
    }
}

extern "C" void kernel_launch(void* const* d_in, const int* in_sizes, int n_in,
                              void* d_out, int out_size, void* d_ws, size_t ws_size,
                              hipStream_t stream) {
    const float* X  = (const float*)d_in[0];
    const int*   ei = (const int*)d_in[1];
    const float* W  = (const float*)d_in[2];
    const float* b  = (const float*)d_in[3];
    float* out = (float*)d_out;
    char* ws = (char*)d_ws;
    const size_t MB = 1u << 20;

    float* At  = (float*)ws;                            // [0, 1M)
    short* Atp = (short*)(ws + 1 * MB);                 // [1M, 1.5M) packed A-frag
    short* Wt2 = (short*)(ws + 1 * MB + 512 * 1024);    // 96 KiB

    k_zero   <<<1024, 256, 0, stream>>>(At);
    k_edges  <<<1, 1024, 0, stream>>>(ei, At);
    k_wt2    <<<192, 256, 0, stream>>>(W, Wt2);
    k_pack_at<<<128, 256, 0, stream>>>(At, Atp);

    if (ws_size >= 194 * MB) {
        // Y1T @2M (64M), Y2 @66M (64M, reused as P1 after k_t), Y2T @130M (64M)
        short* Y1T = (short*)(ws + 2 * MB);
        short* Y2  = (short*)(ws + 66 * MB);
        short* Y2T = (short*)(ws + 130 * MB);
        short* P1  = Y2;   // alias: Y2 dead after k_t
        k_y  <<<2048, 256, 0, stream>>>(X, Wt2, Y1T, Y2);
        k_t  <<<2048, 256, 0, stream>>>(Y2, Y2T);
        k_a1 <<<2048, 256, 0, stream>>>(Atp, Y1T, P1);
        k_a2f<<<2048, 256, 0, stream>>>(X, Atp, Y2T, Wt2, P1, b, out);
    } else {
        short* X1b = (short*)(ws + 2 * MB);
        short* X2b = (short*)(ws + 66 * MB);
        k_agg_fb  <<<4096, 256, 0, stream>>>(X, At, X1b, X2b);
        k_final_fb<<<2048, 256, 0, stream>>>(X, X1b, X2b, Wt2, b, out);
    }
}

// Round 5
// 487.484 us; speedup vs baseline: 1.1727x; 1.0094x over previous
//
#include <hip/hip_runtime.h>
#include <hip/hip_bf16.h>
#include <stdint.h>

// Sizes (fixed by the problem)
#define NN 512
#define DD 128
#define EE 16384

typedef short bf16x8 __attribute__((ext_vector_type(8)));
typedef short bf16x4 __attribute__((ext_vector_type(4)));
typedef float f32x4  __attribute__((ext_vector_type(4)));
typedef unsigned int u32;

__device__ __forceinline__ short f2bf(float f) {
    union { __hip_bfloat16 h; short s; } u;
    u.h = __float2bfloat16(f);
    return u.s;
}
__device__ __forceinline__ u32 pk2(float a, float b) {
    return (u32)(unsigned short)f2bf(a) | ((u32)(unsigned short)f2bf(b) << 16);
}

// async global->LDS 16B copy. LDS dest = wave-uniform base + lane*16 (linear in
// tid); XOR swizzle is applied on the SOURCE chunk index.
typedef __attribute__((address_space(3))) unsigned int lds_u32;
typedef __attribute__((address_space(1))) const unsigned int glb_u32;
__device__ __forceinline__ void gll16(void* l, const void* g) {
    __builtin_amdgcn_global_load_lds((glb_u32*)g, (lds_u32*)l, 16, 0, 0);
}

// ---------------- tiny prep kernels ----------------

__global__ void k_zero(float* __restrict__ At) {
    At[blockIdx.x * 256 + threadIdx.x] = 0.0f;
}

// Build At[dst][src] += 1.  Robust to int32 or int64 input (for int64 LE every
// odd 32-bit word is 0 since values < 512).
__global__ void k_edges(const int* __restrict__ ei, float* __restrict__ At) {
    __shared__ int flag;
    if (threadIdx.x == 0) flag = 0;
    __syncthreads();
    int any = 0;
    for (int i = threadIdx.x; i < EE; i += blockDim.x) any |= ei[2 * i + 1];
    if (any) atomicOr(&flag, 1);
    __syncthreads();
    const bool is32 = (flag != 0);
    for (int e = threadIdx.x; e < EE; e += blockDim.x) {
        int src, dst;
        if (is32) { src = ei[e];     dst = ei[EE + e]; }
        else      { src = ei[2 * e]; dst = ei[2 * (EE + e)]; }
        atomicAdd(&At[dst * NN + src], 1.0f);
    }
}

// Wt2[s][n][d] = bf16(W[(s*128+d)*128 + n])
__global__ void k_wt2(const float* __restrict__ W, short* __restrict__ Wt2) {
    int t = blockIdx.x * 256 + threadIdx.x;     // t = kk*128 + n, kk = s*128+d
    int kk = t >> 7, n = t & 127;
    int s = kk >> 7, d = kk & 127;
    Wt2[s * 16384 + n * 128 + d] = f2bf(W[t]);
}

// Pack At into MFMA A-fragment tile order: tile T = jt*16 + kt covers rows
// jt*16..+16, cols kt*32..+32; lane l holds At[jt*16 + (l&15)][kt*32 + (l>>4)*8 + e].
// A wave's fragment load is 64 lanes x 16B contiguous (1 KB), L2-resident.
__global__ void k_pack_at(const float* __restrict__ At, short* __restrict__ Atp) {
    int t = blockIdx.x * 256 + threadIdx.x;     // 32768 threads
    int T = t >> 6, l = t & 63;
    int row = (T >> 4) * 16 + (l & 15);
    int col = (T & 15) * 32 + (l >> 4) * 8;
    const float* s = &At[row * 512 + col];
    bf16x8 p;
    #pragma unroll
    for (int e = 0; e < 8; ++e) p[e] = f2bf(s[e]);
    *(bf16x8*)&Atp[(size_t)T * 512 + l * 8] = p;
}

// ---------------- k_y: Y1T / Y2 from one pass over X (round-0, proven) --------
// block b: i = b>>2, j0 = (b&3)*128; rows m = (i, j0+r).
// Y1T[i][n][j] = bf16( sum_d X[i][j][d] W1[d][n] )   (transposed in epilogue)
// Y2 [i][j][n] = bf16( sum_d X[i][j][d] W2[d][n] )   (natural)
__global__ __launch_bounds__(256) void k_y(const float* __restrict__ X,
                                           const short* __restrict__ Wt2,
                                           short* __restrict__ Y1T,
                                           short* __restrict__ Y2) {
    __shared__ __align__(16) short Xs[16384];   // [kb][r][64 swizzled]
    __shared__ __align__(16) short Ws[16384];   // [kb][n][64 swizzled]; epilogue scratch

    const int tid  = threadIdx.x;
    const int lane = tid & 63;
    const int wv   = tid >> 6;
    const int wr   = (wv >> 1) * 64;
    const int wc   = (wv & 1) * 64;
    const int lm   = lane & 15;
    const int lq   = lane >> 4;
    const int i  = blockIdx.x >> 2;
    const int j0 = (blockIdx.x & 3) * 128;

    // stage X tile once: fp32 -> bf16, contiguous 64 KB region, coalesced
    #pragma unroll
    for (int it = 0; it < 16; ++it) {
        int g = tid + it * 256;
        int r = g >> 5, c4 = g & 31;
        float4 v = *(const float4*)&X[i * 65536 + (j0 + r) * 128 + c4 * 4];
        int kb = c4 >> 4, c = c4 & 15, p = c >> 1, h2 = c & 1;
        bf16x4 pc; pc[0] = f2bf(v.x); pc[1] = f2bf(v.y); pc[2] = f2bf(v.z); pc[3] = f2bf(v.w);
        *(bf16x4*)&Xs[kb * 8192 + r * 64 + ((p ^ (r & 7)) * 8 + h2 * 4)] = pc;
    }

    #pragma unroll
    for (int s = 1; s <= 2; ++s) {
        // stage W[s] (both kb halves): dest linear, src chunk XOR-swizzled
        #pragma unroll
        for (int it = 0; it < 8; ++it) {
            int slot = it * 256 + tid;              // = kb*1024 + n*8 + pc
            int kb = slot >> 10, rem = slot & 1023;
            int n = rem >> 3, pc = rem & 7;
            gll16(&Ws[slot * 8],
                  &Wt2[s * 16384 + n * 128 + kb * 64 + ((pc ^ (n & 7)) * 8)]);
        }
        __syncthreads();

        f32x4 acc[4][4] = {};
        #pragma unroll
        for (int kb = 0; kb < 2; ++kb)
            #pragma unroll
            for (int ks = 0; ks < 2; ++ks) {
                bf16x8 af[4], bf[4];
                #pragma unroll
                for (int mf = 0; mf < 4; ++mf) {
                    int R = wr + mf * 16 + lm, Cc = ks * 4 + lq;
                    af[mf] = *(const bf16x8*)&Xs[kb * 8192 + R * 64 + (Cc ^ (R & 7)) * 8];
                }
                #pragma unroll
                for (int nf = 0; nf < 4; ++nf) {
                    int R = wc + nf * 16 + lm, Cc = ks * 4 + lq;
                    bf[nf] = *(const bf16x8*)&Ws[kb * 8192 + R * 64 + (Cc ^ (R & 7)) * 8];
                }
                #pragma unroll
                for (int mf = 0; mf < 4; ++mf)
                    #pragma unroll
                    for (int nf = 0; nf < 4; ++nf)
                        acc[mf][nf] = __builtin_amdgcn_mfma_f32_16x16x32_bf16(
                            af[mf], bf[nf], acc[mf][nf], 0, 0, 0);
            }
        __syncthreads();   // MFMA reads of Ws done -> safe to reuse as scratch

        if (s == 1) {
            // transposed epilogue: T[n][j] u32-pairs, XOR-swizzled, b64 writes
            u32* T = (u32*)Ws;
            #pragma unroll
            for (int mf = 0; mf < 4; ++mf)
                #pragma unroll
                for (int nf = 0; nf < 4; ++nf) {
                    int n = wc + nf * 16 + lm;
                    int jb = wr + mf * 16 + lq * 4;   // multiple of 4
                    int w = jb >> 1;                   // even
                    u32 lo = pk2(acc[mf][nf][0], acc[mf][nf][1]);
                    u32 hi = pk2(acc[mf][nf][2], acc[mf][nf][3]);
                    uint2 val; val.x = lo; val.y = hi;
                    *(uint2*)&T[n * 64 + (w ^ (n & 28))] = val;
                }
            __syncthreads();
            #pragma unroll
            for (int it = 0; it < 8; ++it) {
                int ch = tid & 15, n = (tid >> 4) + it * 16;
                uint4 q = *(const uint4*)&T[n * 64 + ((ch * 4) ^ (n & 28))];
                *(uint4*)&Y1T[i * 65536 + n * 512 + j0 + ch * 8] = q;
            }
            __syncthreads();   // before s=2 W staging overwrites T
        } else {
            // natural epilogue via LDS round-trip -> coalesced 16B stores
            #pragma unroll
            for (int mf = 0; mf < 4; ++mf)
                #pragma unroll
                for (int nf = 0; nf < 4; ++nf)
                    #pragma unroll
                    for (int r = 0; r < 4; ++r)
                        Ws[(wr + mf * 16 + lq * 4 + r) * 128 + wc + nf * 16 + lm]
                            = f2bf(acc[mf][nf][r]);
            __syncthreads();
            #pragma unroll
            for (int it = 0; it < 8; ++it) {
                int q = tid + it * 256;
                int row = q >> 4, oc = (q & 15) * 8;
                *(bf16x8*)&Y2[i * 65536 + (j0 + row) * 128 + oc]
                    = *(const bf16x8*)&Ws[row * 128 + oc];
            }
        }
    }
}

// ---------------- k_t: bf16 transpose Y2[k][j][n] -> Y2T[j][n][k] ----------------
// XCD-chunked swizzle: consecutive logical j-groups stay on one XCD.
__global__ __launch_bounds__(256) void k_t(const short* __restrict__ Y2,
                                           short* __restrict__ Y2T) {
    __shared__ __align__(16) u32 U[128 * 64];   // U[n][a]: (k=2a, 2a+1) packed
    const int tid = threadIdx.x;
    const int bid = (blockIdx.x & 7) * 256 + (blockIdx.x >> 3);   // 2048 % 8 == 0
    const int j  = bid >> 2;
    const int k0 = (bid & 3) * 128;

    const int c8 = tid & 15;         // 8-n chunk
    const int a0 = tid >> 4;         // pair index base
    #pragma unroll
    for (int it = 0; it < 4; ++it) {
        int a = a0 + it * 16;        // 0..63
        const short* r0 = &Y2[(size_t)(k0 + 2 * a) * 65536 + j * 128 + c8 * 8];
        bf16x8 A0 = *(const bf16x8*)r0;
        bf16x8 A1 = *(const bf16x8*)(r0 + 65536);
        #pragma unroll
        for (int cc = 0; cc < 8; ++cc) {
            int n = c8 * 8 + cc;
            U[n * 64 + (a ^ (n & 28))] =
                (u32)(unsigned short)A0[cc] | ((u32)(unsigned short)A1[cc] << 16);
        }
    }
    __syncthreads();
    const int ch = tid & 15;
    const int n0 = tid >> 4;
    #pragma unroll
    for (int it = 0; it < 8; ++it) {
        int n = n0 + it * 16;
        uint4 q = *(const uint4*)&U[n * 64 + ((ch * 4) ^ (n & 28))];
        *(uint4*)&Y2T[j * 65536 + n * 512 + k0 + ch * 8] = q;
    }
}

// ---------------- k_a1: P1[i][j][n] = sum_k At[j,k] Y1T[i][n][k] ----------------
// A-fragments direct from packed Atp (L2), ISSUED BEFORE the B prefetch so the
// vmcnt wait for A retires only A (prefetch stays in flight across compute).
// B double-buffered, one barrier per K-step. XCD swizzle keeps the 4 blocks
// sharing Y1T[i] on one XCD.
__global__ __launch_bounds__(256) void k_a1(const short* __restrict__ Atp,
                                            const short* __restrict__ Y1T,
                                            short* __restrict__ P1) {
    __shared__ __align__(16) short sm[16384];   // two 8 KB-pair B buffers

    const int tid  = threadIdx.x;
    const int lane = tid & 63;
    const int wv   = tid >> 6;
    const int wr   = (wv >> 1) * 64;
    const int wc   = (wv & 1) * 64;
    const int lm   = lane & 15;
    const int lq   = lane >> 4;
    const int bid = (blockIdx.x & 7) * 256 + (blockIdx.x >> 3);
    const int i  = bid >> 2;
    const int a0 = (bid & 3) * 128;
    const int jt0 = (a0 >> 4) + (wr >> 4);

    f32x4 acc[4][4] = {};

    // prologue: stage kb=0 into buffer 0
    #pragma unroll
    for (int it = 0; it < 4; ++it) {
        int slot = it * 256 + tid;
        int r = slot >> 3, p = slot & 7;
        int cg = (p ^ (r & 7)) * 8;
        gll16(&sm[slot * 8], &Y1T[i * 65536 + r * 512 + cg]);
    }
    __syncthreads();

    for (int kb = 0; kb < 8; ++kb) {
        short* cur = (kb & 1) ? sm + 8192 : sm;
        short* nxt = (kb & 1) ? sm : sm + 8192;

        // 1) A-fragments FIRST (oldest vmcnt entries)
        bf16x8 afr[2][4];
        #pragma unroll
        for (int ks = 0; ks < 2; ++ks)
            #pragma unroll
            for (int mf = 0; mf < 4; ++mf)
                afr[ks][mf] = *(const bf16x8*)&Atp[(size_t)((jt0 + mf) * 16 + kb * 2 + ks) * 512 + lane * 8];
        __builtin_amdgcn_sched_barrier(0);   // pin issue order: afr before prefetch

        // 2) issue next-tile prefetch (stays in flight through the MFMAs)
        if (kb < 7) {
            const int k0n = (kb + 1) * 64;
            #pragma unroll
            for (int it = 0; it < 4; ++it) {
                int slot = it * 256 + tid;
                int r = slot >> 3, p = slot & 7;
                int cg = (p ^ (r & 7)) * 8;
                gll16(&nxt[slot * 8], &Y1T[i * 65536 + r * 512 + k0n + cg]);
            }
        }

        // 3) compute from cur (LDS) x afr (regs)
        #pragma unroll
        for (int ks = 0; ks < 2; ++ks) {
            bf16x8 bf[4];
            #pragma unroll
            for (int nf = 0; nf < 4; ++nf) {
                int R = wc + nf * 16 + lm, Cc = ks * 4 + lq;
                bf[nf] = *(const bf16x8*)&cur[R * 64 + (Cc ^ (R & 7)) * 8];
            }
            #pragma unroll
            for (int mf = 0; mf < 4; ++mf)
                #pragma unroll
                for (int nf = 0; nf < 4; ++nf)
                    acc[mf][nf] = __builtin_amdgcn_mfma_f32_16x16x32_bf16(
                        afr[ks][mf], bf[nf], acc[mf][nf], 0, 0, 0);
        }
        __syncthreads();   // drains nxt prefetch; orders buffer reuse
    }

    // epilogue: coalesced via LDS round-trip
    #pragma unroll
    for (int mf = 0; mf < 4; ++mf)
        #pragma unroll
        for (int nf = 0; nf < 4; ++nf)
            #pragma unroll
            for (int r = 0; r < 4; ++r)
                sm[(wr + mf * 16 + lq * 4 + r) * 128 + wc + nf * 16 + lm]
                    = f2bf(acc[mf][nf][r]);
    __syncthreads();
    #pragma unroll
    for (int it = 0; it < 8; ++it) {
        int q = tid + it * 256;
        int row = q >> 4, oc = (q & 15) * 8;
        *(bf16x8*)&P1[i * 65536 + (a0 + row) * 128 + oc]
            = *(const bf16x8*)&sm[row * 128 + oc];
    }
}

// ---------------- k_a2f: out = At@Y2T + X@W0 + P1 + b ----------------
// block: j = bid>>2, i0 = (bid&3)*128. Phase 2 double-buffered with Atp-direct
// A-fragments hoisted before the prefetch (vmcnt decoupling); XCD swizzle keeps
// the 4 blocks sharing Y2T[j] on one XCD.
__global__ __launch_bounds__(256) void k_a2f(const float* __restrict__ X,
                                             const short* __restrict__ Atp,
                                             const short* __restrict__ Y2T,
                                             const short* __restrict__ Wt2,
                                             const short* __restrict__ P1,
                                             const float* __restrict__ bias,
                                             float* __restrict__ out) {
    __shared__ __align__(16) short sm[16384];
    short* As = sm;
    short* Bs = sm + 8192;

    const int tid  = threadIdx.x;
    const int lane = tid & 63;
    const int wv   = tid >> 6;
    const int wr   = (wv >> 1) * 64;
    const int wc   = (wv & 1) * 64;
    const int lm   = lane & 15;
    const int lq   = lane >> 4;
    const int bid = (blockIdx.x & 7) * 256 + (blockIdx.x >> 3);
    const int j  = bid >> 2;
    const int i0 = (bid & 3) * 128;

    f32x4 acc[4][4] = {};

    // ---- phase 1: X@W0, K=128 ----
    #pragma unroll
    for (int kb = 0; kb < 2; ++kb) {
        #pragma unroll
        for (int it = 0; it < 8; ++it) {
            int g = tid + it * 256;
            int r = g >> 4, c4 = g & 15;
            float4 v = *(const float4*)&X[(size_t)(i0 + r) * 65536 + j * 128 + kb * 64 + c4 * 4];
            int p = c4 >> 1, h2 = c4 & 1;
            bf16x4 pc; pc[0] = f2bf(v.x); pc[1] = f2bf(v.y); pc[2] = f2bf(v.z); pc[3] = f2bf(v.w);
            *(bf16x4*)&As[r * 64 + ((p ^ (r & 7)) * 8 + h2 * 4)] = pc;
        }
        #pragma unroll
        for (int it = 0; it < 4; ++it) {
            int slot = it * 256 + tid;
            int n = slot >> 3, pc = slot & 7;
            gll16(&Bs[slot * 8], &Wt2[n * 128 + kb * 64 + ((pc ^ (n & 7)) * 8)]);
        }
        __syncthreads();
        #pragma unroll
        for (int ks = 0; ks < 2; ++ks) {
            bf16x8 af[4], bf[4];
            #pragma unroll
            for (int mf = 0; mf < 4; ++mf) {
                int R = wr + mf * 16 + lm, Cc = ks * 4 + lq;
                af[mf] = *(const bf16x8*)&As[R * 64 + (Cc ^ (R & 7)) * 8];
            }
            #pragma unroll
            for (int nf = 0; nf < 4; ++nf) {
                int R = wc + nf * 16 + lm, Cc = ks * 4 + lq;
                bf[nf] = *(const bf16x8*)&Bs[R * 64 + (Cc ^ (R & 7)) * 8];
            }
            #pragma unroll
            for (int mf = 0; mf < 4; ++mf)
                #pragma unroll
                for (int nf = 0; nf < 4; ++nf)
                    acc[mf][nf] = __builtin_amdgcn_mfma_f32_16x16x32_bf16(
                        af[mf], bf[nf], acc[mf][nf], 0, 0, 0);
        }
        __syncthreads();
    }

    // ---- phase 2: At@Y2T, K=512; dbuf B + hoisted Atp-direct A ----
    const int jt0 = (i0 >> 4) + (wr >> 4);
    // prologue: stage kb=0 into buffer 0 (As region, dead after phase 1)
    #pragma unroll
    for (int it = 0; it < 4; ++it) {
        int slot = it * 256 + tid;
        int r = slot >> 3, p = slot & 7;
        int cg = (p ^ (r & 7)) * 8;
        gll16(&sm[slot * 8], &Y2T[j * 65536 + r * 512 + cg]);
    }
    __syncthreads();

    for (int kb = 0; kb < 8; ++kb) {
        short* cur = (kb & 1) ? sm + 8192 : sm;
        short* nxt = (kb & 1) ? sm : sm + 8192;

        // 1) A-fragments FIRST (oldest vmcnt entries)
        bf16x8 afr[2][4];
        #pragma unroll
        for (int ks = 0; ks < 2; ++ks)
            #pragma unroll
            for (int mf = 0; mf < 4; ++mf)
                afr[ks][mf] = *(const bf16x8*)&Atp[(size_t)((jt0 + mf) * 16 + kb * 2 + ks) * 512 + lane * 8];
        __builtin_amdgcn_sched_barrier(0);   // pin issue order: afr before prefetch

        // 2) issue next-tile prefetch
        if (kb < 7) {
            const int k0n = (kb + 1) * 64;
            #pragma unroll
            for (int it = 0; it < 4; ++it) {
                int slot = it * 256 + tid;
                int r = slot >> 3, p = slot & 7;
                int cg = (p ^ (r & 7)) * 8;
                gll16(&nxt[slot * 8], &Y2T[j * 65536 + r * 512 + k0n + cg]);
            }
        }

        // 3) compute from cur (LDS) x afr (regs)
        #pragma unroll
        for (int ks = 0; ks < 2; ++ks) {
            bf16x8 bf[4];
            #pragma unroll
            for (int nf = 0; nf < 4; ++nf) {
                int R = wc + nf * 16 + lm, Cc = ks * 4 + lq;
                bf[nf] = *(const bf16x8*)&cur[R * 64 + (Cc ^ (R & 7)) * 8];
            }
            #pragma unroll
            for (int mf = 0; mf < 4; ++mf)
                #pragma unroll
                for (int nf = 0; nf < 4; ++nf)
                    acc[mf][nf] = __builtin_amdgcn_mfma_f32_16x16x32_bf16(
                        afr[ks][mf], bf[nf], acc[mf][nf], 0, 0, 0);
        }
        __syncthreads();
    }

    // ---- fused epilogue: + P1 + bias -> fp32 out ----
    #pragma unroll
    for (int mf = 0; mf < 4; ++mf)
        #pragma unroll
        for (int nf = 0; nf < 4; ++nf)
            #pragma unroll
            for (int r = 0; r < 4; ++r)
                sm[(wr + mf * 16 + lq * 4 + r) * 128 + wc + nf * 16 + lm]
                    = f2bf(acc[mf][nf][r]);
    __syncthreads();
    #pragma unroll
    for (int it = 0; it < 8; ++it) {
        int q = tid + it * 256;
        int row = q >> 4, oc = (q & 15) * 8;
        bf16x8 vs = *(const bf16x8*)&sm[row * 128 + oc];
        bf16x8 vpl = *(const bf16x8*)&P1[(size_t)(i0 + row) * 65536 + j * 128 + oc];
        float4 b0 = *(const float4*)&bias[oc];
        float4 b1 = *(const float4*)&bias[oc + 4];
        union { short s; __hip_bfloat16 h; } cs, cp;
        float o[8];
        #pragma unroll
        for (int e = 0; e < 8; ++e) {
            cs.s = vs[e]; cp.s = vpl[e];
            o[e] = __bfloat162float(cs.h) + __bfloat162float(cp.h);
        }
        o[0] += b0.x; o[1] += b0.y; o[2] += b0.z; o[3] += b0.w;
        o[4] += b1.x; o[5] += b1.y; o[6] += b1.z; o[7] += b1.w;
        float* op = &out[(size_t)(i0 + row) * 65536 + j * 128 + oc];
        float4 w0; w0.x = o[0]; w0.y = o[1]; w0.z = o[2]; w0.w = o[3];
        float4 w1; w1.x = o[4]; w1.y = o[5]; w1.z = o[6]; w1.w = o[7];
        *(float4*)op = w0;
        *(float4*)(op + 4) = w1;
    }
}

// ================= fallback path (round-1, proven, 130 MiB ws) =================

__global__ __launch_bounds__(256) void k_agg_fb(const float* __restrict__ X,
                                                const float* __restrict__ At,
                                                short* __restrict__ X1b,
                                                short* __restrict__ X2b) {
    __shared__ short As[128 * 72];
    __shared__ short Bs[128 * 72];
    const int tid  = threadIdx.x;
    const int lane = tid & 63;
    const int wv   = tid >> 6;
    const int wr   = (wv >> 1) * 64;
    const int wc   = (wv & 1) * 64;
    const int lm   = lane & 15;
    const int lq   = lane >> 4;
    int a0, Bbase, Bks, Cbase, Crs;
    short* Cp;
    const int bidx = blockIdx.x;
    if (bidx < 2048) {
        int i = bidx >> 2, jt = bidx & 3;
        a0 = jt * 128; Bbase = i * 65536; Bks = 128;
        Cbase = i * 65536 + jt * 16384; Crs = 128; Cp = X1b;
    } else {
        int bb = bidx - 2048;
        int j = bb >> 2, it = bb & 3;
        a0 = it * 128; Bbase = j * 128; Bks = 65536;
        Cbase = it * 8388608 + j * 128; Crs = 65536; Cp = X2b;
    }
    f32x4 acc[4][4] = {};
    const int d  = tid & 127;
    const int kh = tid >> 7;
    for (int kb = 0; kb < 8; ++kb) {
        const int k0 = kb * 64;
        #pragma unroll
        for (int it8 = 0; it8 < 8; ++it8) {
            int g = tid + it8 * 256;
            int r = g >> 4, kq = (g & 15) * 4;
            float4 v = *(const float4*)&At[(a0 + r) * 512 + k0 + kq];
            bf16x4 p; p[0] = f2bf(v.x); p[1] = f2bf(v.y); p[2] = f2bf(v.z); p[3] = f2bf(v.w);
            *(bf16x4*)&As[r * 72 + kq] = p;
        }
        #pragma unroll
        for (int gi = 0; gi < 4; ++gi) {
            int kg = kh * 4 + gi;
            bf16x8 p;
            #pragma unroll
            for (int jj = 0; jj < 8; ++jj)
                p[jj] = f2bf(X[Bbase + (k0 + kg * 8 + jj) * Bks + d]);
            *(bf16x8*)&Bs[d * 72 + kg * 8] = p;
        }
        __syncthreads();
        #pragma unroll
        for (int ks = 0; ks < 2; ++ks) {
            bf16x8 af[4], bfr[4];
            #pragma unroll
            for (int mf = 0; mf < 4; ++mf)
                af[mf] = *(const bf16x8*)&As[(wr + mf * 16 + lm) * 72 + ks * 32 + lq * 8];
            #pragma unroll
            for (int nf = 0; nf < 4; ++nf)
                bfr[nf] = *(const bf16x8*)&Bs[(wc + nf * 16 + lm) * 72 + ks * 32 + lq * 8];
            #pragma unroll
            for (int mf = 0; mf < 4; ++mf)
                #pragma unroll
                for (int nf = 0; nf < 4; ++nf)
                    acc[mf][nf] = __builtin_amdgcn_mfma_f32_16x16x32_bf16(
                        af[mf], bfr[nf], acc[mf][nf], 0, 0, 0);
        }
        __syncthreads();
    }
    #pragma unroll
    for (int mf = 0; mf < 4; ++mf)
        #pragma unroll
        for (int nf = 0; nf < 4; ++nf)
            #pragma unroll
            for (int r = 0; r < 4; ++r) {
                int row = wr + mf * 16 + lq * 4 + r;
                int col = wc + nf * 16 + lm;
                Cp[Cbase + row * Crs + col] = f2bf(acc[mf][nf][r]);
            }
}

__global__ __launch_bounds__(256) void k_final_fb(const float* __restrict__ X,
                                                  const short* __restrict__ X1b,
                                                  const short* __restrict__ X2b,
                                                  const short* __restrict__ Wt2,
                                                  const float* __restrict__ bias,
                                                  float* __restrict__ out) {
    __shared__ short As[128 * 72];
    __shared__ short Ws[128 * 72];
    const int tid  = threadIdx.x;
    const int lane = tid & 63;
    const int wv   = tid >> 6;
    const int wr   = (wv >> 1) * 64;
    const int wc   = (wv & 1) * 64;
    const int lm   = lane & 15;
    const int lq   = lane >> 4;
    const int m0   = blockIdx.x * 128;
    f32x4 acc[4][4] = {};
    for (int ph = 0; ph < 6; ++ph) {
        const int s = ph >> 1, h = ph & 1;
        if (s == 0) {
            #pragma unroll
            for (int it8 = 0; it8 < 8; ++it8) {
                int g = tid + it8 * 256;
                int r = g >> 4, kq = (g & 15) * 4;
                float4 v = *(const float4*)&X[(m0 + r) * 128 + h * 64 + kq];
                bf16x4 p; p[0] = f2bf(v.x); p[1] = f2bf(v.y); p[2] = f2bf(v.z); p[3] = f2bf(v.w);
                *(bf16x4*)&As[r * 72 + kq] = p;
            }
        } else {
            const short* src = (s == 1) ? X1b : X2b;
            #pragma unroll
            for (int it4 = 0; it4 < 4; ++it4) {
                int g = tid + it4 * 256;
                int r = g >> 3, ko = (g & 7) * 8;
                *(bf16x8*)&As[r * 72 + ko] =
                    *(const bf16x8*)&src[(m0 + r) * 128 + h * 64 + ko];
            }
        }
        #pragma unroll
        for (int it4 = 0; it4 < 4; ++it4) {
            int g = tid + it4 * 256;
            int n = g >> 3, ko = (g & 7) * 8;
            *(bf16x8*)&Ws[n * 72 + ko] =
                *(const bf16x8*)&Wt2[s * 16384 + n * 128 + h * 64 + ko];
        }
        __syncthreads();
        #pragma unroll
        for (int ks = 0; ks < 2; ++ks) {
            bf16x8 af[4], bfr[4];
            #pragma unroll
            for (int mf = 0; mf < 4; ++mf)
                af[mf] = *(const bf16x8*)&As[(wr + mf * 16 + lm) * 72 + ks * 32 + lq * 8];
            #pragma unroll
            for (int nf = 0; nf < 4; ++nf)
                bfr[nf] = *(const bf16x8*)&Ws[(wc + nf * 16 + lm) * 72 + ks * 32 + lq * 8];
            #pragma unroll
            for (int mf = 0; mf < 4; ++mf)
                #pragma unroll
                for (int nf = 0; nf < 4; ++nf)
                    acc[mf][nf] = __builtin_amdgcn_mfma_f32_16x16x32_bf16(
                        af[mf], bfr[nf], acc[mf][nf], 0, 0, 0);
        }
        __syncthreads();
    }
    #pragma unroll
    for (int nf = 0; nf < 4; ++nf) {
        float bv = bias[wc + nf * 16 + lm];
        #pragma unroll
        for (int mf = 0; mf < 4; ++mf)
            #pragma unroll
            for (int r = 0; r < 4; ++r) {
                int row = m0 + wr + mf * 16 + lq * 4 + r;
                int col = wc + nf * 16 + lm;
                out[row * 128 + col] = acc[mf][nf][r] + bv;
            }
    }
}

extern "C" void kernel_launch(void* const* d_in, const int* in_sizes, int n_in,
                              void* d_out, int out_size, void* d_ws, size_t ws_size,
                              hipStream_t stream) {
    const float* X  = (const float*)d_in[0];
    const int*   ei = (const int*)d_in[1];
    const float* W  = (const float*)d_in[2];
    const float* b  = (const float*)d_in[3];
    float* out = (float*)d_out;
    char* ws = (char*)d_ws;
    const size_t MB = 1u << 20;

    float* At  = (float*)ws;                            // [0, 1M)
    short* Atp = (short*)(ws + 1 * MB);                 // [1M, 1.5M) packed A-frag
    short* Wt2 = (short*)(ws + 1 * MB + 512 * 1024);    // 96 KiB

    k_zero   <<<1024, 256, 0, stream>>>(At);
    k_edges  <<<1, 1024, 0, stream>>>(ei, At);
    k_wt2    <<<192, 256, 0, stream>>>(W, Wt2);
    k_pack_at<<<128, 256, 0, stream>>>(At, Atp);

    if (ws_size >= 194 * MB) {
        // Y1T @2M (64M), Y2 @66M (64M, reused as P1 after k_t), Y2T @130M (64M)
        short* Y1T = (short*)(ws + 2 * MB);
        short* Y2  = (short*)(ws + 66 * MB);
        short* Y2T = (short*)(ws + 130 * MB);
        short* P1  = Y2;   // alias: Y2 dead after k_t
        k_y  <<<2048, 256, 0, stream>>>(X, Wt2, Y1T, Y2);
        k_t  <<<2048, 256, 0, stream>>>(Y2, Y2T);
        k_a1 <<<2048, 256, 0, stream>>>(Atp, Y1T, P1);
        k_a2f<<<2048, 256, 0, stream>>>(X, Atp, Y2T, Wt2, P1, b, out);
    } else {
        short* X1b = (short*)(ws + 2 * MB);
        short* X2b = (short*)(ws + 66 * MB);
        k_agg_fb  <<<4096, 256, 0, stream>>>(X, At, X1b, X2b);
        k_final_fb<<<2048, 256, 0, stream>>>(X, X1b, X2b, Wt2, b, out);
    }
}